// Round 7
// baseline (576.822 us; speedup 1.0000x reference)
//
#include <hip/hip_runtime.h>
#include <hip/hip_bf16.h>
#include <math.h>

// ---------------------------------------------------------------------------
// Round 16. R15 measured 479.9us (best). mgemm_qkv top: 99.6us, MfmaUtil
// 21.5% == the DS-pipe ceiling of the 128^2 tile (12KB LDS/wave-iter vs
// 80cyc MFMA -> 80/560 ~= 21%). GEMMs are LDS-BW-bound, not sync-bound.
// Change (all GEMM kernels): B (weights, L2-resident: 256KB/bn-block
// re-read by 64 bm-blocks) now loaded DIRECT global->reg per fragment
// with 1-iter register prefetch; LDS stages A only (6KB/wave-iter, 2x
// cut in the binding resource). Bs bank conflicts eliminated. LDS/block
// 32KB -> 16KB. vmcnt(0)+raw-barrier pipeline unchanged (covers B too).
// attn / cvt_all proven, unchanged.
// ---------------------------------------------------------------------------

#define SEQ     2048
#define BATCH   4
#define NH      16
#define CDIM    1024
#define MROWS   8192

typedef __bf16 bf16x8 __attribute__((ext_vector_type(8)));
typedef float  floatx4 __attribute__((ext_vector_type(4)));
typedef float  floatx16 __attribute__((ext_vector_type(16)));
typedef unsigned int u32;

__device__ __forceinline__ unsigned short f2bf(float f) {
    __bf16 h = (__bf16)f;                      // RNE, HW cvt on gfx950
    return __builtin_bit_cast(unsigned short, h);
}
__device__ __forceinline__ float fexp2(float x) {   // 2^x
    float r; asm("v_exp_f32 %0, %1" : "=v"(r) : "v"(x)); return r;
}
__device__ __forceinline__ float frcp(float x) {    // ~1ulp 1/x
    float r; asm("v_rcp_f32 %0, %1" : "=v"(r) : "v"(x)); return r;
}
__device__ __forceinline__ u32 cvtpk(float lo, float hi) {  // 2xbf16 word
    u32 w; asm("v_cvt_pk_bf16_f32 %0, %1, %2" : "=v"(w) : "v"(lo), "v"(hi));
    return w;
}
__device__ __forceinline__ floatx4 mfma16(bf16x8 a, bf16x8 b, floatx4 c) {
    return __builtin_amdgcn_mfma_f32_16x16x32_bf16(a, b, c, 0, 0, 0);
}
__device__ __forceinline__ floatx16 mfma32(bf16x8 a, bf16x8 b, floatx16 c) {
    return __builtin_amdgcn_mfma_f32_32x32x16_bf16(a, b, c, 0, 0, 0);
}
// async global->LDS, 16B/lane; LDS dest wave-uniform base + lane*16
__device__ __forceinline__ void gld16(void* lds, const void* g) {
    __builtin_amdgcn_global_load_lds(
        (const __attribute__((address_space(1))) u32*)g,
        (__attribute__((address_space(3))) u32*)lds, 16, 0, 0);
}
// counted-wait + raw barrier (no compiler vmcnt(0) drain)
__device__ __forceinline__ void wait_vm0_barrier() {
    asm volatile("s_waitcnt vmcnt(0)" ::: "memory");
    __builtin_amdgcn_s_barrier();
    __builtin_amdgcn_sched_barrier(0);
}
__device__ __forceinline__ void raw_barrier() {
    __builtin_amdgcn_s_barrier();
    __builtin_amdgcn_sched_barrier(0);
}

// ============================================================
// bf16 MFMA GEMM NT: A staged via gld16 (double-buffer LDS),
// B (weights, L2-hot) direct global->reg with 1-iter prefetch.
// C[m,n] = sum_k A[m,k]*B[n,k] (+bias)
// ============================================================
template <int OUTMODE, bool BIAS>
__global__ __launch_bounds__(256) void mgemm(
    const unsigned short* __restrict__ A,
    const unsigned short* __restrict__ B,
    const float* __restrict__ bias,
    void* __restrict__ C, int ldc,
    int K)
{
    __shared__ __align__(16) unsigned short As[2][128 * 32];

    const int tid  = threadIdx.x;
    const int lane = tid & 63;
    const int wave = tid >> 6;
    const int l16  = lane & 15;
    const int quad = lane >> 4;
    const int wm = (wave >> 1) * 64, wn = (wave & 1) * 64;
    const int bm = blockIdx.y, bn = blockIdx.x;

    const unsigned short* Ag = A + (size_t)(bm * 128) * K;
    const unsigned short* Bg = B + (size_t)(bn * 128) * K;

    const int srow0 = wave * 32 + (lane >> 2);
    const int scol  = (lane & 3) * 8;
    const unsigned short* gA0 = Ag + (size_t)srow0 * K + scol;
    const unsigned short* gA1 = Ag + (size_t)(srow0 + 16) * K + scol;

    auto stageA = [&](int b, int kt) {
        gld16(&As[b][(wave * 2 + 0) * 512], gA0 + kt);
        gld16(&As[b][(wave * 2 + 1) * 512], gA1 + kt);
    };

    // per-lane B fragment bases (row = wn + nt*16 + l16, col = quad*8)
    const unsigned short* gBf[4];
    #pragma unroll
    for (int nt = 0; nt < 4; ++nt)
        gBf[nt] = Bg + (size_t)(wn + nt * 16 + l16) * K + quad * 8;

    floatx4 acc[4][4] = {};
    const int NK = K >> 5;

    stageA(0, 0);
    bf16x8 bcur[4];
    #pragma unroll
    for (int nt = 0; nt < 4; ++nt)
        bcur[nt] = *(const bf16x8*)(gBf[nt]);
    wait_vm0_barrier();

    for (int i = 0; i < NK; ++i) {
        const int cur = i & 1;
        bf16x8 bnxt[4];
        if (i + 1 < NK) {
            stageA(cur ^ 1, (i + 1) * 32);
            #pragma unroll
            for (int nt = 0; nt < 4; ++nt)
                bnxt[nt] = *(const bf16x8*)(gBf[nt] + (i + 1) * 32);
        }

        bf16x8 af[4];
        #pragma unroll
        for (int mt = 0; mt < 4; ++mt)
            af[mt] = *(const bf16x8*)&As[cur][(wm + mt * 16 + l16) * 32 + quad * 8];
        #pragma unroll
        for (int mt = 0; mt < 4; ++mt)
            #pragma unroll
            for (int nt = 0; nt < 4; ++nt)
                acc[mt][nt] = mfma16(af[mt], bcur[nt], acc[mt][nt]);

        if (i + 1 < NK) {
            wait_vm0_barrier();
            #pragma unroll
            for (int nt = 0; nt < 4; ++nt) bcur[nt] = bnxt[nt];
        } else {
            raw_barrier();
        }
    }

    #pragma unroll
    for (int nt = 0; nt < 4; ++nt) {
        const int gcol = bn * 128 + wn + nt * 16 + l16;
        const float bv = BIAS ? bias[gcol] : 0.0f;
        #pragma unroll
        for (int mt = 0; mt < 4; ++mt) {
            #pragma unroll
            for (int r = 0; r < 4; ++r) {
                const int grow = bm * 128 + wm + mt * 16 + quad * 4 + r;
                float v = acc[mt][nt][r] + bv;
                if (OUTMODE == 0)
                    ((float*)C)[(size_t)grow * ldc + gcol] = v;
                else
                    ((unsigned short*)C)[(size_t)grow * ldc + gcol] = f2bf(v);
            }
        }
    }
}

// ============================================================
// Fused SwiGLU GEMM, 128x64 N-tile, A-only LDS + direct-B + fast silu:
// hid[m,n] = silu(A@W1^T + b1) * (A@W2^T + b2)
// ============================================================
__global__ __launch_bounds__(256) void mgemm_glu(
    const unsigned short* __restrict__ A,
    const unsigned short* __restrict__ B1,
    const unsigned short* __restrict__ B2,
    const float* __restrict__ bias1,
    const float* __restrict__ bias2,
    unsigned short* __restrict__ C, int ldc,
    int K)
{
    __shared__ __align__(16) unsigned short As[2][128 * 32];

    const int tid  = threadIdx.x;
    const int lane = tid & 63;
    const int wave = tid >> 6;
    const int l16  = lane & 15;
    const int quad = lane >> 4;
    const int wm = (wave >> 1) * 64, wn = (wave & 1) * 32;
    const int bm = blockIdx.y, bn = blockIdx.x;

    const unsigned short* Ag  = A  + (size_t)(bm * 128) * K;
    const unsigned short* B1g = B1 + (size_t)(bn * 64) * K;
    const unsigned short* B2g = B2 + (size_t)(bn * 64) * K;

    const int arow = wave * 32 + (lane >> 2);
    const int scol = (lane & 3) * 8;
    const unsigned short* gA0 = Ag + (size_t)arow * K + scol;
    const unsigned short* gA1 = Ag + (size_t)(arow + 16) * K + scol;

    auto stageA = [&](int b, int kt) {
        gld16(&As[b][(wave * 2 + 0) * 512], gA0 + kt);
        gld16(&As[b][(wave * 2 + 1) * 512], gA1 + kt);
    };

    const unsigned short* gB1f[2];
    const unsigned short* gB2f[2];
    #pragma unroll
    for (int nt = 0; nt < 2; ++nt) {
        gB1f[nt] = B1g + (size_t)(wn + nt * 16 + l16) * K + quad * 8;
        gB2f[nt] = B2g + (size_t)(wn + nt * 16 + l16) * K + quad * 8;
    }

    floatx4 acc1[4][2] = {};
    floatx4 acc2[4][2] = {};
    const int NK = K >> 5;

    stageA(0, 0);
    bf16x8 b1c[2], b2c[2];
    #pragma unroll
    for (int nt = 0; nt < 2; ++nt) {
        b1c[nt] = *(const bf16x8*)(gB1f[nt]);
        b2c[nt] = *(const bf16x8*)(gB2f[nt]);
    }
    wait_vm0_barrier();

    for (int i = 0; i < NK; ++i) {
        const int cur = i & 1;
        bf16x8 b1n[2], b2n[2];
        if (i + 1 < NK) {
            stageA(cur ^ 1, (i + 1) * 32);
            #pragma unroll
            for (int nt = 0; nt < 2; ++nt) {
                b1n[nt] = *(const bf16x8*)(gB1f[nt] + (i + 1) * 32);
                b2n[nt] = *(const bf16x8*)(gB2f[nt] + (i + 1) * 32);
            }
        }

        bf16x8 af[4];
        #pragma unroll
        for (int mt = 0; mt < 4; ++mt)
            af[mt] = *(const bf16x8*)&As[cur][(wm + mt * 16 + l16) * 32 + quad * 8];
        #pragma unroll
        for (int mt = 0; mt < 4; ++mt)
            #pragma unroll
            for (int nt = 0; nt < 2; ++nt) {
                acc1[mt][nt] = mfma16(af[mt], b1c[nt], acc1[mt][nt]);
                acc2[mt][nt] = mfma16(af[mt], b2c[nt], acc2[mt][nt]);
            }

        if (i + 1 < NK) {
            wait_vm0_barrier();
            #pragma unroll
            for (int nt = 0; nt < 2; ++nt) { b1c[nt] = b1n[nt]; b2c[nt] = b2n[nt]; }
        } else {
            raw_barrier();
        }
    }

    #pragma unroll
    for (int nt = 0; nt < 2; ++nt) {
        const int gcol = bn * 64 + wn + nt * 16 + l16;
        const float b1 = bias1[gcol];
        const float b2 = bias2[gcol];
        #pragma unroll
        for (int mt = 0; mt < 4; ++mt) {
            #pragma unroll
            for (int r = 0; r < 4; ++r) {
                const int grow = bm * 128 + wm + mt * 16 + quad * 4 + r;
                const float x1 = acc1[mt][nt][r] + b1;
                const float x2 = acc2[mt][nt][r] + b2;
                // silu(x1)*x2 via HW exp2/rcp (log2e folded)
                const float e = fexp2(x1 * -1.44269504088896f);
                const float v = x1 * frcp(1.0f + e) * x2;
                C[(size_t)grow * ldc + gcol] = f2bf(v);
            }
        }
    }
}

// ============================================================
// QKV GEMM, A-only LDS + direct-B, fused epilogues:
//  q/k: fp32 RoPE (table), q pre-scaled by 0.125*log2e, -> Qb/Kb [bh][n][64]
//  v:   LDS-transposed (reuses dead As) -> Vtb [bh][d][n], 16B stores
// ============================================================
__global__ __launch_bounds__(256) void mgemm_qkv(
    const unsigned short* __restrict__ A,
    const unsigned short* __restrict__ B,
    const float* __restrict__ tab,
    unsigned short* __restrict__ Qb,
    unsigned short* __restrict__ Kb,
    unsigned short* __restrict__ Vtb)
{
    __shared__ __align__(16) unsigned short As[2][128 * 32];

    const int tid  = threadIdx.x;
    const int lane = tid & 63;
    const int wave = tid >> 6;
    const int l16  = lane & 15;
    const int quad = lane >> 4;
    const int wm = (wave >> 1) * 64, wn = (wave & 1) * 64;
    const int bm = blockIdx.y, bn = blockIdx.x;
    const int K = CDIM;

    const unsigned short* Ag = A + (size_t)(bm * 128) * K;
    const unsigned short* Bg = B + (size_t)(bn * 128) * K;

    const int srow0 = wave * 32 + (lane >> 2);
    const int scol  = (lane & 3) * 8;
    const unsigned short* gA0 = Ag + (size_t)srow0 * K + scol;
    const unsigned short* gA1 = Ag + (size_t)(srow0 + 16) * K + scol;

    auto stageA = [&](int b, int kt) {
        gld16(&As[b][(wave * 2 + 0) * 512], gA0 + kt);
        gld16(&As[b][(wave * 2 + 1) * 512], gA1 + kt);
    };

    const unsigned short* gBf[4];
    #pragma unroll
    for (int nt = 0; nt < 4; ++nt)
        gBf[nt] = Bg + (size_t)(wn + nt * 16 + l16) * K + quad * 8;

    floatx4 acc[4][4] = {};
    const int NK = K >> 5;

    stageA(0, 0);
    bf16x8 bcur[4];
    #pragma unroll
    for (int nt = 0; nt < 4; ++nt)
        bcur[nt] = *(const bf16x8*)(gBf[nt]);
    wait_vm0_barrier();

    for (int i = 0; i < NK; ++i) {
        const int cur = i & 1;
        bf16x8 bnxt[4];
        if (i + 1 < NK) {
            stageA(cur ^ 1, (i + 1) * 32);
            #pragma unroll
            for (int nt = 0; nt < 4; ++nt)
                bnxt[nt] = *(const bf16x8*)(gBf[nt] + (i + 1) * 32);
        }

        bf16x8 af[4];
        #pragma unroll
        for (int mt = 0; mt < 4; ++mt)
            af[mt] = *(const bf16x8*)&As[cur][(wm + mt * 16 + l16) * 32 + quad * 8];
        #pragma unroll
        for (int mt = 0; mt < 4; ++mt)
            #pragma unroll
            for (int nt = 0; nt < 4; ++nt)
                acc[mt][nt] = mfma16(af[mt], bcur[nt], acc[mt][nt]);

        if (i + 1 < NK) {
            wait_vm0_barrier();
            #pragma unroll
            for (int nt = 0; nt < 4; ++nt) bcur[nt] = bnxt[nt];
        } else {
            raw_barrier();
        }
    }

    // part is BLOCK-uniform: 128-col blocks never straddle a 1024 boundary.
    const int colbase0 = bn * 128;
    const int part = colbase0 >> 10;            // 0=q 1=k 2=v

    if (part == 2) {
        // ---- V: transpose via LDS (As dead), write Vtb [bh][d][n] ----
        unsigned short* T = &As[0][0];          // 4 waves x 64d x 16n ushorts
        #pragma unroll
        for (int mt = 0; mt < 4; ++mt) {
            __syncthreads();
            #pragma unroll
            for (int nt = 0; nt < 4; ++nt) {
                ushort4 pk;
                pk.x = f2bf(acc[mt][nt][0]); pk.y = f2bf(acc[mt][nt][1]);
                pk.z = f2bf(acc[mt][nt][2]); pk.w = f2bf(acc[mt][nt][3]);
                *(ushort4*)&T[((wave * 64 + nt * 16 + l16) * 16) + quad * 4] = pk;
            }
            __syncthreads();
            // 256 threads: w2 = tid>>6 (wave-tile), d = tid&63; 32B per thread
            const int w2 = tid >> 6, d = tid & 63;
            const int nrow0 = bm * 128 + (w2 >> 1) * 64 + mt * 16;
            const int b = nrow0 >> 11, n0 = nrow0 & 2047;
            const int h2 = ((bn * 128 + (w2 & 1) * 64) & 1023) >> 6;
            unsigned short* dst = Vtb +
                ((size_t)(b * NH + h2) * 64 + d) * 2048 + n0;
            const int tb = (w2 * 64 + d) * 16;
            *(uint4*)dst       = *(const uint4*)&T[tb];
            *(uint4*)(dst + 8) = *(const uint4*)&T[tb + 8];
        }
    } else {
        // ---- q/k: fp32 RoPE; q scaled by 0.125*log2e (exp2 softmax) ----
        const float qscale = (part == 0) ? 0.125f * 1.44269504088896f : 1.0f;
        const int h = ((colbase0 + wn) & 1023) >> 6;
        #pragma unroll
        for (int mt = 0; mt < 4; ++mt) {
            #pragma unroll
            for (int r = 0; r < 4; ++r) {
                const int grow = bm * 128 + wm + mt * 16 + quad * 4 + r;
                const int b = grow >> 11, n = grow & 2047;
                unsigned short* dst =
                    (part == 0 ? Qb : Kb) + ((size_t)(b * NH + h) * 2048 + n) * 64;
                #pragma unroll
                for (int nt = 0; nt < 2; ++nt) {
                    const int i = nt * 16 + l16;          // 0..31
                    const float c  = tab[(n * 32 + i) * 2];
                    const float sn = tab[(n * 32 + i) * 2 + 1];
                    const float x1 = acc[mt][nt][r];
                    const float x2v = acc[mt][nt + 2][r];
                    dst[i]      = f2bf((x1 * c - x2v * sn) * qscale);
                    dst[i + 32] = f2bf((x2v * c + x1 * sn) * qscale);
                }
            }
        }
    }
}

// ============================================================
// MFMA flash attention v4 (PROVEN R14/R15): 128q blocks, 32x32x16,
// P in registers via cvt_pk + permlane32_swap. Grid (bh, qt).
// ============================================================
__global__ __launch_bounds__(256) void attn_mfma(
    const unsigned short* __restrict__ Qb,
    const unsigned short* __restrict__ Kb,
    const unsigned short* __restrict__ Vtb,
    unsigned short* __restrict__ Ob)
{
    const int bh = blockIdx.x;        // 0..63  (x-major: same-bh -> same XCD)
    const int qt = blockIdx.y;        // 0..15
    const int tid = threadIdx.x;
    const int lane = tid & 63, wave = tid >> 6;
    const int r32 = lane & 31, hi = lane >> 5;
    const int qrow = wave * 32 + r32; // this lane's query row in LDS

    __shared__ unsigned short QP[128][72];  // Q staging (held all iters)
    __shared__ unsigned short Ks[64][72];   // K tile [key][dim]
    __shared__ unsigned short Vs[64][72];   // V^T tile [dim][key]

    const unsigned short* Qg = Qb + ((size_t)bh * 2048 + qt * 128) * 64;
    const unsigned short* Kg = Kb + (size_t)bh * 2048 * 64;
    const unsigned short* Vg = Vtb + (size_t)bh * 64 * 2048;

    // stage Q tile 128x64
    #pragma unroll
    for (int rep = 0; rep < 4; ++rep) {
        const int c = tid + rep * 256;
        const int r = c >> 3, d0 = (c & 7) * 8;
        *(uint4*)&QP[r][d0] = *(const uint4*)(Qg + (size_t)r * 64 + d0);
    }

    // K/V staging slots for this thread (2 b128 each per tile)
    const int c0 = tid, c1 = tid + 256;
    const int kr0 = c0 >> 3, kd0 = (c0 & 7) * 8;
    const int kr1 = c1 >> 3, kd1 = (c1 & 7) * 8;

    // T14 prefetch tile 0 into regs
    uint4 ka0 = *(const uint4*)(Kg + (size_t)kr0 * 64 + kd0);
    uint4 ka1 = *(const uint4*)(Kg + (size_t)kr1 * 64 + kd1);
    uint4 va0 = *(const uint4*)(Vg + (size_t)kr0 * 2048 + kd0);
    uint4 va1 = *(const uint4*)(Vg + (size_t)kr1 * 2048 + kd1);

    __syncthreads();   // Q tile ready

    // Q B-frags (rows = wave's 32 queries), held for all iterations
    bf16x8 bq[4];
    #pragma unroll
    for (int f = 0; f < 4; ++f)
        bq[f] = *(const bf16x8*)&QP[qrow][f * 16 + hi * 8];

    floatx16 o0 = {}, o1 = {};      // O^T[d][q]: d-tiles 0..31 / 32..63
    float l_acc = 0.0f;

    for (int kt = 0; kt < 32; ++kt) {
        __syncthreads();   // prev tile's Ks/Vs frag reads complete
        *(uint4*)&Ks[kr0][kd0] = ka0;
        *(uint4*)&Ks[kr1][kd1] = ka1;
        *(uint4*)&Vs[kr0][kd0] = va0;
        *(uint4*)&Vs[kr1][kd1] = va1;
        if (kt + 1 < 32) {           // T14: issue next-tile loads now,
            const size_t nb = (size_t)(kt + 1) * 64;     // land during compute
            ka0 = *(const uint4*)(Kg + (nb + kr0) * 64 + kd0);
            ka1 = *(const uint4*)(Kg + (nb + kr1) * 64 + kd1);
            va0 = *(const uint4*)(Vg + (size_t)kr0 * 2048 + nb + kd0);
            va1 = *(const uint4*)(Vg + (size_t)kr1 * 2048 + nb + kd1);
        }
        __syncthreads();   // tile ready

        // ---- per 32-key subtile: S^T -> exp2 -> in-reg P -> PV ----
        #pragma unroll
        for (int t = 0; t < 2; ++t) {
            floatx16 s = {};
            #pragma unroll
            for (int f = 0; f < 4; ++f) {
                const bf16x8 ak = *(const bf16x8*)&Ks[t * 32 + r32][f * 16 + hi * 8];
                s = mfma32(ak, bq[f], s);
            }
            // p = exp2(s); rowsum
            float p[16];
            float rs = 0.0f;
            #pragma unroll
            for (int g = 0; g < 16; ++g) { p[g] = fexp2(s[g]); rs += p[g]; }
            l_acc += rs;
            // pack to bf16 words and swap halves across hi
            u32 w0 = cvtpk(p[0], p[1]),   w2 = cvtpk(p[4], p[5]);
            u32 w1 = cvtpk(p[2], p[3]),   w3 = cvtpk(p[6], p[7]);
            u32 w4 = cvtpk(p[8], p[9]),   w6 = cvtpk(p[12], p[13]);
            u32 w5 = cvtpk(p[10], p[11]), w7 = cvtpk(p[14], p[15]);
            asm("v_permlane32_swap_b32 %0, %1" : "+v"(w0), "+v"(w2));
            asm("v_permlane32_swap_b32 %0, %1" : "+v"(w1), "+v"(w3));
            asm("v_permlane32_swap_b32 %0, %1" : "+v"(w4), "+v"(w6));
            asm("v_permlane32_swap_b32 %0, %1" : "+v"(w5), "+v"(w7));
            uint4 u0; u0.x = w0; u0.y = w1; u0.z = w2; u0.w = w3;
            uint4 u1; u1.x = w4; u1.y = w5; u1.z = w6; u1.w = w7;
            const bf16x8 bp0 = __builtin_bit_cast(bf16x8, u0);  // keys t*32 + slot0
            const bf16x8 bp1 = __builtin_bit_cast(bf16x8, u1);  // keys t*32 + slot1
            // PV for this subtile's two 16-key slots (f = 2t, 2t+1)
            {
                const int f0 = 2 * t, f1 = 2 * t + 1;
                const bf16x8 av00 = *(const bf16x8*)&Vs[r32][f0 * 16 + hi * 8];
                const bf16x8 av01 = *(const bf16x8*)&Vs[32 + r32][f0 * 16 + hi * 8];
                o0 = mfma32(av00, bp0, o0);
                o1 = mfma32(av01, bp0, o1);
                const bf16x8 av10 = *(const bf16x8*)&Vs[r32][f1 * 16 + hi * 8];
                const bf16x8 av11 = *(const bf16x8*)&Vs[32 + r32][f1 * 16 + hi * 8];
                o0 = mfma32(av10, bp1, o0);
                o1 = mfma32(av11, bp1, o1);
            }
        }
    }

    // epilogue: lane's query = wave*32 + r32; lanes l/l+32 hold disjoint key
    // halves of the same query -> one shfl to complete l.
    const float l_tot = l_acc + __shfl_xor(l_acc, 32);
    const float inv = 1.0f / l_tot;
    const int b = bh >> 4, h = bh & 15;
    unsigned short* orow = Ob +
        (size_t)(b * SEQ + qt * 128 + qrow) * CDIM + h * 64;
    #pragma unroll
    for (int u = 0; u < 2; ++u) {
        const floatx16 ov = u ? o1 : o0;
        #pragma unroll
        for (int g = 0; g < 4; ++g) {
            ushort4 pk;
            pk.x = f2bf(ov[4 * g + 0] * inv); pk.y = f2bf(ov[4 * g + 1] * inv);
            pk.z = f2bf(ov[4 * g + 2] * inv); pk.w = f2bf(ov[4 * g + 3] * inv);
            // d = u*32 + 8g + 4*hi + (0..3)
            *(ushort4*)(orow + u * 32 + 8 * g + 4 * hi) = pk;
        }
    }
}

// ============================================================
// One-shot fp32 -> bf16 for all six tensors (block-uniform segments);
// RoPE table (fp64 angles)
// ============================================================
__global__ __launch_bounds__(256) void cvt_all(
    const float* __restrict__ x,    const float* __restrict__ qkv,
    const float* __restrict__ proj, const float* __restrict__ w1,
    const float* __restrict__ w2,   const float* __restrict__ w3,
    unsigned short* __restrict__ xb,    unsigned short* __restrict__ qkvb,
    unsigned short* __restrict__ projb, unsigned short* __restrict__ w1b,
    unsigned short* __restrict__ w2b,   unsigned short* __restrict__ w3b)
{
    const size_t i = ((size_t)blockIdx.x * 256 + threadIdx.x) * 4;
    const float* src; unsigned short* dst; size_t off;
    if      (i <  8388608) { src = x;    dst = xb;    off = 0; }
    else if (i < 11534336) { src = qkv;  dst = qkvb;  off = 8388608; }
    else if (i < 12582912) { src = proj; dst = projb; off = 11534336; }
    else if (i < 14680064) { src = w1;   dst = w1b;   off = 12582912; }
    else if (i < 16777216) { src = w2;   dst = w2b;   off = 14680064; }
    else                   { src = w3;   dst = w3b;   off = 16777216; }
    const size_t j = i - off;
    const float4 f = *(const float4*)(src + j);
    ushort4 o; o.x = f2bf(f.x); o.y = f2bf(f.y); o.z = f2bf(f.z); o.w = f2bf(f.w);
    *(ushort4*)(dst + j) = o;
}

__global__ __launch_bounds__(256) void rope_table(float* __restrict__ tab)
{
    const int idx = blockIdx.x * 256 + threadIdx.x;   // < 65536
    const int i = idx & 31, n = idx >> 5;
    const double f = (double)n * pow(10000.0, -(double)(2 * i) / 64.0);
    tab[idx * 2]     = (float)cos(f);
    tab[idx * 2 + 1] = (float)sin(f);
}

// ============================================================
// kernel_launch
// ============================================================
extern "C" void kernel_launch(void* const* d_in, const int* in_sizes, int n_in,
                              void* d_out, int out_size, void* d_ws, size_t ws_size,
                              hipStream_t stream)
{
    const float* x      = (const float*)d_in[0];
    const float* qkv_w  = (const float*)d_in[1];
    const float* proj_w = (const float*)d_in[2];
    const float* proj_b = (const float*)d_in[3];
    const float* w1_w   = (const float*)d_in[4];
    const float* w1_b   = (const float*)d_in[5];
    const float* w2_w   = (const float*)d_in[6];
    const float* w2_b   = (const float*)d_in[7];
    const float* w3_w   = (const float*)d_in[8];
    const float* w3_b   = (const float*)d_in[9];
    float* out = (float*)d_out;

    char* ws = (char*)d_ws;
    unsigned short* Qb    = (unsigned short*)(ws);              // [0,16M)
    unsigned short* Kb    = (unsigned short*)(ws + 16777216);   // [16,32M)
    unsigned short* Vtb   = (unsigned short*)(ws + 33554432);   // [32,48M)
    unsigned short* Ob    = (unsigned short*)(ws + 50331648);   // [48,64M)
    unsigned short* out1b = (unsigned short*)(ws + 67108864);   // [64,80M)
    unsigned short* w1b   = (unsigned short*)(ws + 83886080);   // [80,84M)
    unsigned short* w2b   = (unsigned short*)(ws + 88080384);   // [84,88M)
    unsigned short* w3b   = (unsigned short*)(ws + 92274688);   // [88,92M)
    unsigned short* projb = (unsigned short*)(ws + 96468992);   // [92,94M)
    unsigned short* xb    = (unsigned short*)(ws + 98566144);   // [94,110M)
    unsigned short* wqkvb = (unsigned short*)(ws + 115343360);  // [110,116M)
    float*          tab   = (float*)(ws + 121634816);           // [116,116.5M)
    unsigned short* hid   = (unsigned short*)(ws);              // [0,32M)

    const dim3 blk(256);

    // all fp32->bf16 conversions in one dispatch (18874368 elems / 1024)
    cvt_all<<<dim3(18432), blk, 0, stream>>>(
        x, qkv_w, proj_w, w1_w, w2_w, w3_w,
        xb, wqkvb, projb, w1b, w2b, w3b);
    rope_table<<<dim3(256), blk, 0, stream>>>(tab);

    // 1) QKV GEMM + fused rope/scale + coalesced transpose scatter
    mgemm_qkv<<<dim3(24, 64), blk, 0, stream>>>(xb, wqkvb, tab, Qb, Kb, Vtb);
    // 2) MFMA flash attention; grid (bh, qt) -> same-bh blocks co-XCD
    attn_mfma<<<dim3(BATCH * NH, SEQ / 128), blk, 0, stream>>>(Qb, Kb, Vtb, Ob);
    // 3) out1b = Ob @ projb^T + proj_b (bf16)
    mgemm<1, true><<<dim3(8, 64), blk, 0, stream>>>(
        Ob, projb, proj_b, out1b, CDIM, CDIM);
    // 4) hid = silu(out1b@w1^T + b1) * (out1b@w2^T + b2)  [fused, no x2]
    mgemm_glu<<<dim3(32, 64), blk, 0, stream>>>(
        out1b, w1b, w2b, w1_b, w2_b, hid, 2048, CDIM);
    // 5) out = hid @ w3b^T + w3_b (fp32 -> d_out)
    mgemm<0, true><<<dim3(8, 64), blk, 0, stream>>>(
        hid, w3b, w3_b, out, CDIM, 2048);
}

// Round 8
// 478.464 us; speedup vs baseline: 1.2056x; 1.2056x over previous
//
#include <hip/hip_runtime.h>
#include <hip/hip_bf16.h>
#include <math.h>

// ---------------------------------------------------------------------------
// Round 17. R16 regressed (576.8): direct-B per-lane loads are address-
// divergent (64 cache lines/instr, stride 2KB) -> latency-bound (MfmaUtil
// AND VALUBusy both ~18%). REVERTED to R15 staging (B via coalesced gld16).
// Revised model: R15's 2-phase vmcnt(0) exposes ~100+ cyc of load latency
// per iter (loads get only one MFMA phase). Fix = T4 counted vmcnt:
// triple-buffer LDS, 2-deep prefetch, wait vmcnt(4) (tile i+1 done, tile
// i+2 stays in flight across the barrier; never vmcnt(0) mid-loop).
// LDS 48KB/block (3 blocks/CU). Applied to mgemm/mgemm_glu/mgemm_qkv.
// attn v4 / cvt_all / fast-silu epilogue proven, unchanged.
// ---------------------------------------------------------------------------

#define SEQ     2048
#define BATCH   4
#define NH      16
#define CDIM    1024
#define MROWS   8192

typedef __bf16 bf16x8 __attribute__((ext_vector_type(8)));
typedef float  floatx4 __attribute__((ext_vector_type(4)));
typedef float  floatx16 __attribute__((ext_vector_type(16)));
typedef unsigned int u32;

__device__ __forceinline__ unsigned short f2bf(float f) {
    __bf16 h = (__bf16)f;                      // RNE, HW cvt on gfx950
    return __builtin_bit_cast(unsigned short, h);
}
__device__ __forceinline__ float fexp2(float x) {   // 2^x
    float r; asm("v_exp_f32 %0, %1" : "=v"(r) : "v"(x)); return r;
}
__device__ __forceinline__ float frcp(float x) {    // ~1ulp 1/x
    float r; asm("v_rcp_f32 %0, %1" : "=v"(r) : "v"(x)); return r;
}
__device__ __forceinline__ u32 cvtpk(float lo, float hi) {  // 2xbf16 word
    u32 w; asm("v_cvt_pk_bf16_f32 %0, %1, %2" : "=v"(w) : "v"(lo), "v"(hi));
    return w;
}
__device__ __forceinline__ floatx4 mfma16(bf16x8 a, bf16x8 b, floatx4 c) {
    return __builtin_amdgcn_mfma_f32_16x16x32_bf16(a, b, c, 0, 0, 0);
}
__device__ __forceinline__ floatx16 mfma32(bf16x8 a, bf16x8 b, floatx16 c) {
    return __builtin_amdgcn_mfma_f32_32x32x16_bf16(a, b, c, 0, 0, 0);
}
// async global->LDS, 16B/lane; LDS dest wave-uniform base + lane*16
__device__ __forceinline__ void gld16(void* lds, const void* g) {
    __builtin_amdgcn_global_load_lds(
        (const __attribute__((address_space(1))) u32*)g,
        (__attribute__((address_space(3))) u32*)lds, 16, 0, 0);
}
// counted waits + raw barrier (T4: never drain vmcnt to 0 mid-loop)
__device__ __forceinline__ void wait_vm4_barrier() {   // 4 loads may stay in flight
    asm volatile("s_waitcnt vmcnt(4)" ::: "memory");
    __builtin_amdgcn_s_barrier();
    __builtin_amdgcn_sched_barrier(0);
}
__device__ __forceinline__ void wait_vm0_barrier() {   // epilogue drain only
    asm volatile("s_waitcnt vmcnt(0)" ::: "memory");
    __builtin_amdgcn_s_barrier();
    __builtin_amdgcn_sched_barrier(0);
}

// ============================================================
// bf16 MFMA GEMM NT, triple-buffer counted-vmcnt pipeline:
// C[m,n] = sum_k A[m,k]*B[n,k] (+bias)
// ============================================================
template <int OUTMODE, bool BIAS>
__global__ __launch_bounds__(256) void mgemm(
    const unsigned short* __restrict__ A,
    const unsigned short* __restrict__ B,
    const float* __restrict__ bias,
    void* __restrict__ C, int ldc,
    int K)
{
    __shared__ __align__(16) unsigned short As[3][128 * 32];
    __shared__ __align__(16) unsigned short Bs[3][128 * 32];

    const int tid  = threadIdx.x;
    const int lane = tid & 63;
    const int wave = tid >> 6;
    const int l16  = lane & 15;
    const int quad = lane >> 4;
    const int wm = (wave >> 1) * 64, wn = (wave & 1) * 64;
    const int bm = blockIdx.y, bn = blockIdx.x;

    const unsigned short* Ag = A + (size_t)(bm * 128) * K;
    const unsigned short* Bg = B + (size_t)(bn * 128) * K;

    const int srow0 = wave * 32 + (lane >> 2);
    const int scol  = (lane & 3) * 8;
    const unsigned short* gA0 = Ag + (size_t)srow0 * K + scol;
    const unsigned short* gA1 = Ag + (size_t)(srow0 + 16) * K + scol;
    const unsigned short* gB0 = Bg + (size_t)srow0 * K + scol;
    const unsigned short* gB1 = Bg + (size_t)(srow0 + 16) * K + scol;

    auto stage = [&](int b, int kt) {              // 4 gld16 per wave
        gld16(&As[b][(wave * 2 + 0) * 512], gA0 + kt);
        gld16(&As[b][(wave * 2 + 1) * 512], gA1 + kt);
        gld16(&Bs[b][(wave * 2 + 0) * 512], gB0 + kt);
        gld16(&Bs[b][(wave * 2 + 1) * 512], gB1 + kt);
    };

    floatx4 acc[4][4] = {};
    const int NK = K >> 5;                         // >= 32 here

    stage(0, 0);
    stage(1, 32);
    wait_vm4_barrier();                            // tile0 landed, tile1 in flight

    for (int i = 0; i < NK; ++i) {
        const int cur = i % 3;
        if (i + 2 < NK) stage((i + 2) % 3, (i + 2) * 32);

        bf16x8 af[4], bfr[4];
        #pragma unroll
        for (int mt = 0; mt < 4; ++mt)
            af[mt] = *(const bf16x8*)&As[cur][(wm + mt * 16 + l16) * 32 + quad * 8];
        #pragma unroll
        for (int nt = 0; nt < 4; ++nt)
            bfr[nt] = *(const bf16x8*)&Bs[cur][(wn + nt * 16 + l16) * 32 + quad * 8];
        #pragma unroll
        for (int mt = 0; mt < 4; ++mt)
            #pragma unroll
            for (int nt = 0; nt < 4; ++nt)
                acc[mt][nt] = mfma16(af[mt], bfr[nt], acc[mt][nt]);

        if (i + 2 < NK)      wait_vm4_barrier();   // tile i+1 ready, i+2 in flight
        else if (i + 1 < NK) wait_vm0_barrier();   // drain last tile
        // last iteration: no barrier needed (epilogue is register-only)
    }

    #pragma unroll
    for (int nt = 0; nt < 4; ++nt) {
        const int gcol = bn * 128 + wn + nt * 16 + l16;
        const float bv = BIAS ? bias[gcol] : 0.0f;
        #pragma unroll
        for (int mt = 0; mt < 4; ++mt) {
            #pragma unroll
            for (int r = 0; r < 4; ++r) {
                const int grow = bm * 128 + wm + mt * 16 + quad * 4 + r;
                float v = acc[mt][nt][r] + bv;
                if (OUTMODE == 0)
                    ((float*)C)[(size_t)grow * ldc + gcol] = v;
                else
                    ((unsigned short*)C)[(size_t)grow * ldc + gcol] = f2bf(v);
            }
        }
    }
}

// ============================================================
// Fused SwiGLU GEMM, 128x64 N-tile, triple-buffer pipeline + fast silu:
// hid[m,n] = silu(A@W1^T + b1) * (A@W2^T + b2)
// ============================================================
__global__ __launch_bounds__(256) void mgemm_glu(
    const unsigned short* __restrict__ A,
    const unsigned short* __restrict__ B1,
    const unsigned short* __restrict__ B2,
    const float* __restrict__ bias1,
    const float* __restrict__ bias2,
    unsigned short* __restrict__ C, int ldc,
    int K)
{
    __shared__ __align__(16) unsigned short As[3][128 * 32];
    __shared__ __align__(16) unsigned short B1s[3][64 * 32];
    __shared__ __align__(16) unsigned short B2s[3][64 * 32];

    const int tid  = threadIdx.x;
    const int lane = tid & 63;
    const int wave = tid >> 6;
    const int l16  = lane & 15;
    const int quad = lane >> 4;
    const int wm = (wave >> 1) * 64, wn = (wave & 1) * 32;
    const int bm = blockIdx.y, bn = blockIdx.x;

    const unsigned short* Ag  = A  + (size_t)(bm * 128) * K;
    const unsigned short* B1g = B1 + (size_t)(bn * 64) * K;
    const unsigned short* B2g = B2 + (size_t)(bn * 64) * K;

    const int arow = wave * 32 + (lane >> 2);
    const int brow = wave * 16 + (lane >> 2);
    const int scol = (lane & 3) * 8;
    const unsigned short* gA0 = Ag  + (size_t)arow * K + scol;
    const unsigned short* gA1 = Ag  + (size_t)(arow + 16) * K + scol;
    const unsigned short* gB1 = B1g + (size_t)brow * K + scol;
    const unsigned short* gB2 = B2g + (size_t)brow * K + scol;

    auto stage = [&](int b, int kt) {              // 4 gld16 per wave
        gld16(&As[b][(wave * 2 + 0) * 512], gA0 + kt);
        gld16(&As[b][(wave * 2 + 1) * 512], gA1 + kt);
        gld16(&B1s[b][wave * 512], gB1 + kt);
        gld16(&B2s[b][wave * 512], gB2 + kt);
    };

    floatx4 acc1[4][2] = {};
    floatx4 acc2[4][2] = {};
    const int NK = K >> 5;

    stage(0, 0);
    stage(1, 32);
    wait_vm4_barrier();

    for (int i = 0; i < NK; ++i) {
        const int cur = i % 3;
        if (i + 2 < NK) stage((i + 2) % 3, (i + 2) * 32);

        bf16x8 af[4], b1f[2], b2f[2];
        #pragma unroll
        for (int mt = 0; mt < 4; ++mt)
            af[mt] = *(const bf16x8*)&As[cur][(wm + mt * 16 + l16) * 32 + quad * 8];
        #pragma unroll
        for (int nt = 0; nt < 2; ++nt) {
            b1f[nt] = *(const bf16x8*)&B1s[cur][(wn + nt * 16 + l16) * 32 + quad * 8];
            b2f[nt] = *(const bf16x8*)&B2s[cur][(wn + nt * 16 + l16) * 32 + quad * 8];
        }
        #pragma unroll
        for (int mt = 0; mt < 4; ++mt)
            #pragma unroll
            for (int nt = 0; nt < 2; ++nt) {
                acc1[mt][nt] = mfma16(af[mt], b1f[nt], acc1[mt][nt]);
                acc2[mt][nt] = mfma16(af[mt], b2f[nt], acc2[mt][nt]);
            }

        if (i + 2 < NK)      wait_vm4_barrier();
        else if (i + 1 < NK) wait_vm0_barrier();
    }

    #pragma unroll
    for (int nt = 0; nt < 2; ++nt) {
        const int gcol = bn * 64 + wn + nt * 16 + l16;
        const float b1 = bias1[gcol];
        const float b2 = bias2[gcol];
        #pragma unroll
        for (int mt = 0; mt < 4; ++mt) {
            #pragma unroll
            for (int r = 0; r < 4; ++r) {
                const int grow = bm * 128 + wm + mt * 16 + quad * 4 + r;
                const float x1 = acc1[mt][nt][r] + b1;
                const float x2 = acc2[mt][nt][r] + b2;
                // silu(x1)*x2 via HW exp2/rcp (log2e folded)
                const float e = fexp2(x1 * -1.44269504088896f);
                const float v = x1 * frcp(1.0f + e) * x2;
                C[(size_t)grow * ldc + gcol] = f2bf(v);
            }
        }
    }
}

// ============================================================
// QKV GEMM, triple-buffer pipeline, fused epilogues:
//  q/k: fp32 RoPE (table), q pre-scaled by 0.125*log2e, -> Qb/Kb [bh][n][64]
//  v:   LDS-transposed (reuses dead As) -> Vtb [bh][d][n], 16B stores
// ============================================================
__global__ __launch_bounds__(256) void mgemm_qkv(
    const unsigned short* __restrict__ A,
    const unsigned short* __restrict__ B,
    const float* __restrict__ tab,
    unsigned short* __restrict__ Qb,
    unsigned short* __restrict__ Kb,
    unsigned short* __restrict__ Vtb)
{
    __shared__ __align__(16) unsigned short As[3][128 * 32];
    __shared__ __align__(16) unsigned short Bs[3][128 * 32];

    const int tid  = threadIdx.x;
    const int lane = tid & 63;
    const int wave = tid >> 6;
    const int l16  = lane & 15;
    const int quad = lane >> 4;
    const int wm = (wave >> 1) * 64, wn = (wave & 1) * 64;
    const int bm = blockIdx.y, bn = blockIdx.x;
    const int K = CDIM;

    const unsigned short* Ag = A + (size_t)(bm * 128) * K;
    const unsigned short* Bg = B + (size_t)(bn * 128) * K;

    const int srow0 = wave * 32 + (lane >> 2);
    const int scol  = (lane & 3) * 8;
    const unsigned short* gA0 = Ag + (size_t)srow0 * K + scol;
    const unsigned short* gA1 = Ag + (size_t)(srow0 + 16) * K + scol;
    const unsigned short* gB0 = Bg + (size_t)srow0 * K + scol;
    const unsigned short* gB1 = Bg + (size_t)(srow0 + 16) * K + scol;

    auto stage = [&](int b, int kt) {
        gld16(&As[b][(wave * 2 + 0) * 512], gA0 + kt);
        gld16(&As[b][(wave * 2 + 1) * 512], gA1 + kt);
        gld16(&Bs[b][(wave * 2 + 0) * 512], gB0 + kt);
        gld16(&Bs[b][(wave * 2 + 1) * 512], gB1 + kt);
    };

    floatx4 acc[4][4] = {};
    const int NK = K >> 5;

    stage(0, 0);
    stage(1, 32);
    wait_vm4_barrier();

    for (int i = 0; i < NK; ++i) {
        const int cur = i % 3;
        if (i + 2 < NK) stage((i + 2) % 3, (i + 2) * 32);

        bf16x8 af[4], bfr[4];
        #pragma unroll
        for (int mt = 0; mt < 4; ++mt)
            af[mt] = *(const bf16x8*)&As[cur][(wm + mt * 16 + l16) * 32 + quad * 8];
        #pragma unroll
        for (int nt = 0; nt < 4; ++nt)
            bfr[nt] = *(const bf16x8*)&Bs[cur][(wn + nt * 16 + l16) * 32 + quad * 8];
        #pragma unroll
        for (int mt = 0; mt < 4; ++mt)
            #pragma unroll
            for (int nt = 0; nt < 4; ++nt)
                acc[mt][nt] = mfma16(af[mt], bfr[nt], acc[mt][nt]);

        if (i + 2 < NK)      wait_vm4_barrier();
        else if (i + 1 < NK) wait_vm0_barrier();
    }

    // part is BLOCK-uniform: 128-col blocks never straddle a 1024 boundary.
    const int colbase0 = bn * 128;
    const int part = colbase0 >> 10;            // 0=q 1=k 2=v

    if (part == 2) {
        // ---- V: transpose via LDS (As dead), write Vtb [bh][d][n] ----
        unsigned short* T = &As[0][0];          // 4 waves x 64d x 16n ushorts
        #pragma unroll
        for (int mt = 0; mt < 4; ++mt) {
            __syncthreads();
            #pragma unroll
            for (int nt = 0; nt < 4; ++nt) {
                ushort4 pk;
                pk.x = f2bf(acc[mt][nt][0]); pk.y = f2bf(acc[mt][nt][1]);
                pk.z = f2bf(acc[mt][nt][2]); pk.w = f2bf(acc[mt][nt][3]);
                *(ushort4*)&T[((wave * 64 + nt * 16 + l16) * 16) + quad * 4] = pk;
            }
            __syncthreads();
            // 256 threads: w2 = tid>>6 (wave-tile), d = tid&63; 32B per thread
            const int w2 = tid >> 6, d = tid & 63;
            const int nrow0 = bm * 128 + (w2 >> 1) * 64 + mt * 16;
            const int b = nrow0 >> 11, n0 = nrow0 & 2047;
            const int h2 = ((bn * 128 + (w2 & 1) * 64) & 1023) >> 6;
            unsigned short* dst = Vtb +
                ((size_t)(b * NH + h2) * 64 + d) * 2048 + n0;
            const int tb = (w2 * 64 + d) * 16;
            *(uint4*)dst       = *(const uint4*)&T[tb];
            *(uint4*)(dst + 8) = *(const uint4*)&T[tb + 8];
        }
    } else {
        // ---- q/k: fp32 RoPE; q scaled by 0.125*log2e (exp2 softmax) ----
        const float qscale = (part == 0) ? 0.125f * 1.44269504088896f : 1.0f;
        const int h = ((colbase0 + wn) & 1023) >> 6;
        #pragma unroll
        for (int mt = 0; mt < 4; ++mt) {
            #pragma unroll
            for (int r = 0; r < 4; ++r) {
                const int grow = bm * 128 + wm + mt * 16 + quad * 4 + r;
                const int b = grow >> 11, n = grow & 2047;
                unsigned short* dst =
                    (part == 0 ? Qb : Kb) + ((size_t)(b * NH + h) * 2048 + n) * 64;
                #pragma unroll
                for (int nt = 0; nt < 2; ++nt) {
                    const int i = nt * 16 + l16;          // 0..31
                    const float c  = tab[(n * 32 + i) * 2];
                    const float sn = tab[(n * 32 + i) * 2 + 1];
                    const float x1 = acc[mt][nt][r];
                    const float x2v = acc[mt][nt + 2][r];
                    dst[i]      = f2bf((x1 * c - x2v * sn) * qscale);
                    dst[i + 32] = f2bf((x2v * c + x1 * sn) * qscale);
                }
            }
        }
    }
}

// ============================================================
// MFMA flash attention v4 (PROVEN R14/R15): 128q blocks, 32x32x16,
// P in registers via cvt_pk + permlane32_swap. Grid (bh, qt).
// ============================================================
__global__ __launch_bounds__(256) void attn_mfma(
    const unsigned short* __restrict__ Qb,
    const unsigned short* __restrict__ Kb,
    const unsigned short* __restrict__ Vtb,
    unsigned short* __restrict__ Ob)
{
    const int bh = blockIdx.x;        // 0..63  (x-major: same-bh -> same XCD)
    const int qt = blockIdx.y;        // 0..15
    const int tid = threadIdx.x;
    const int lane = tid & 63, wave = tid >> 6;
    const int r32 = lane & 31, hi = lane >> 5;
    const int qrow = wave * 32 + r32; // this lane's query row in LDS

    __shared__ unsigned short QP[128][72];  // Q staging (held all iters)
    __shared__ unsigned short Ks[64][72];   // K tile [key][dim]
    __shared__ unsigned short Vs[64][72];   // V^T tile [dim][key]

    const unsigned short* Qg = Qb + ((size_t)bh * 2048 + qt * 128) * 64;
    const unsigned short* Kg = Kb + (size_t)bh * 2048 * 64;
    const unsigned short* Vg = Vtb + (size_t)bh * 64 * 2048;

    // stage Q tile 128x64
    #pragma unroll
    for (int rep = 0; rep < 4; ++rep) {
        const int c = tid + rep * 256;
        const int r = c >> 3, d0 = (c & 7) * 8;
        *(uint4*)&QP[r][d0] = *(const uint4*)(Qg + (size_t)r * 64 + d0);
    }

    // K/V staging slots for this thread (2 b128 each per tile)
    const int c0 = tid, c1 = tid + 256;
    const int kr0 = c0 >> 3, kd0 = (c0 & 7) * 8;
    const int kr1 = c1 >> 3, kd1 = (c1 & 7) * 8;

    // T14 prefetch tile 0 into regs
    uint4 ka0 = *(const uint4*)(Kg + (size_t)kr0 * 64 + kd0);
    uint4 ka1 = *(const uint4*)(Kg + (size_t)kr1 * 64 + kd1);
    uint4 va0 = *(const uint4*)(Vg + (size_t)kr0 * 2048 + kd0);
    uint4 va1 = *(const uint4*)(Vg + (size_t)kr1 * 2048 + kd1);

    __syncthreads();   // Q tile ready

    // Q B-frags (rows = wave's 32 queries), held for all iterations
    bf16x8 bq[4];
    #pragma unroll
    for (int f = 0; f < 4; ++f)
        bq[f] = *(const bf16x8*)&QP[qrow][f * 16 + hi * 8];

    floatx16 o0 = {}, o1 = {};      // O^T[d][q]: d-tiles 0..31 / 32..63
    float l_acc = 0.0f;

    for (int kt = 0; kt < 32; ++kt) {
        __syncthreads();   // prev tile's Ks/Vs frag reads complete
        *(uint4*)&Ks[kr0][kd0] = ka0;
        *(uint4*)&Ks[kr1][kd1] = ka1;
        *(uint4*)&Vs[kr0][kd0] = va0;
        *(uint4*)&Vs[kr1][kd1] = va1;
        if (kt + 1 < 32) {           // T14: issue next-tile loads now,
            const size_t nb = (size_t)(kt + 1) * 64;     // land during compute
            ka0 = *(const uint4*)(Kg + (nb + kr0) * 64 + kd0);
            ka1 = *(const uint4*)(Kg + (nb + kr1) * 64 + kd1);
            va0 = *(const uint4*)(Vg + (size_t)kr0 * 2048 + nb + kd0);
            va1 = *(const uint4*)(Vg + (size_t)kr1 * 2048 + nb + kd1);
        }
        __syncthreads();   // tile ready

        // ---- per 32-key subtile: S^T -> exp2 -> in-reg P -> PV ----
        #pragma unroll
        for (int t = 0; t < 2; ++t) {
            floatx16 s = {};
            #pragma unroll
            for (int f = 0; f < 4; ++f) {
                const bf16x8 ak = *(const bf16x8*)&Ks[t * 32 + r32][f * 16 + hi * 8];
                s = mfma32(ak, bq[f], s);
            }
            // p = exp2(s); rowsum
            float p[16];
            float rs = 0.0f;
            #pragma unroll
            for (int g = 0; g < 16; ++g) { p[g] = fexp2(s[g]); rs += p[g]; }
            l_acc += rs;
            // pack to bf16 words and swap halves across hi
            u32 w0 = cvtpk(p[0], p[1]),   w2 = cvtpk(p[4], p[5]);
            u32 w1 = cvtpk(p[2], p[3]),   w3 = cvtpk(p[6], p[7]);
            u32 w4 = cvtpk(p[8], p[9]),   w6 = cvtpk(p[12], p[13]);
            u32 w5 = cvtpk(p[10], p[11]), w7 = cvtpk(p[14], p[15]);
            asm("v_permlane32_swap_b32 %0, %1" : "+v"(w0), "+v"(w2));
            asm("v_permlane32_swap_b32 %0, %1" : "+v"(w1), "+v"(w3));
            asm("v_permlane32_swap_b32 %0, %1" : "+v"(w4), "+v"(w6));
            asm("v_permlane32_swap_b32 %0, %1" : "+v"(w5), "+v"(w7));
            uint4 u0; u0.x = w0; u0.y = w1; u0.z = w2; u0.w = w3;
            uint4 u1; u1.x = w4; u1.y = w5; u1.z = w6; u1.w = w7;
            const bf16x8 bp0 = __builtin_bit_cast(bf16x8, u0);  // keys t*32 + slot0
            const bf16x8 bp1 = __builtin_bit_cast(bf16x8, u1);  // keys t*32 + slot1
            // PV for this subtile's two 16-key slots (f = 2t, 2t+1)
            {
                const int f0 = 2 * t, f1 = 2 * t + 1;
                const bf16x8 av00 = *(const bf16x8*)&Vs[r32][f0 * 16 + hi * 8];
                const bf16x8 av01 = *(const bf16x8*)&Vs[32 + r32][f0 * 16 + hi * 8];
                o0 = mfma32(av00, bp0, o0);
                o1 = mfma32(av01, bp0, o1);
                const bf16x8 av10 = *(const bf16x8*)&Vs[r32][f1 * 16 + hi * 8];
                const bf16x8 av11 = *(const bf16x8*)&Vs[32 + r32][f1 * 16 + hi * 8];
                o0 = mfma32(av10, bp1, o0);
                o1 = mfma32(av11, bp1, o1);
            }
        }
    }

    // epilogue: lane's query = wave*32 + r32; lanes l/l+32 hold disjoint key
    // halves of the same query -> one shfl to complete l.
    const float l_tot = l_acc + __shfl_xor(l_acc, 32);
    const float inv = 1.0f / l_tot;
    const int b = bh >> 4, h = bh & 15;
    unsigned short* orow = Ob +
        (size_t)(b * SEQ + qt * 128 + qrow) * CDIM + h * 64;
    #pragma unroll
    for (int u = 0; u < 2; ++u) {
        const floatx16 ov = u ? o1 : o0;
        #pragma unroll
        for (int g = 0; g < 4; ++g) {
            ushort4 pk;
            pk.x = f2bf(ov[4 * g + 0] * inv); pk.y = f2bf(ov[4 * g + 1] * inv);
            pk.z = f2bf(ov[4 * g + 2] * inv); pk.w = f2bf(ov[4 * g + 3] * inv);
            // d = u*32 + 8g + 4*hi + (0..3)
            *(ushort4*)(orow + u * 32 + 8 * g + 4 * hi) = pk;
        }
    }
}

// ============================================================
// One-shot fp32 -> bf16 for all six tensors (block-uniform segments);
// RoPE table (fp64 angles)
// ============================================================
__global__ __launch_bounds__(256) void cvt_all(
    const float* __restrict__ x,    const float* __restrict__ qkv,
    const float* __restrict__ proj, const float* __restrict__ w1,
    const float* __restrict__ w2,   const float* __restrict__ w3,
    unsigned short* __restrict__ xb,    unsigned short* __restrict__ qkvb,
    unsigned short* __restrict__ projb, unsigned short* __restrict__ w1b,
    unsigned short* __restrict__ w2b,   unsigned short* __restrict__ w3b)
{
    const size_t i = ((size_t)blockIdx.x * 256 + threadIdx.x) * 4;
    const float* src; unsigned short* dst; size_t off;
    if      (i <  8388608) { src = x;    dst = xb;    off = 0; }
    else if (i < 11534336) { src = qkv;  dst = qkvb;  off = 8388608; }
    else if (i < 12582912) { src = proj; dst = projb; off = 11534336; }
    else if (i < 14680064) { src = w1;   dst = w1b;   off = 12582912; }
    else if (i < 16777216) { src = w2;   dst = w2b;   off = 14680064; }
    else                   { src = w3;   dst = w3b;   off = 16777216; }
    const size_t j = i - off;
    const float4 f = *(const float4*)(src + j);
    ushort4 o; o.x = f2bf(f.x); o.y = f2bf(f.y); o.z = f2bf(f.z); o.w = f2bf(f.w);
    *(ushort4*)(dst + j) = o;
}

__global__ __launch_bounds__(256) void rope_table(float* __restrict__ tab)
{
    const int idx = blockIdx.x * 256 + threadIdx.x;   // < 65536
    const int i = idx & 31, n = idx >> 5;
    const double f = (double)n * pow(10000.0, -(double)(2 * i) / 64.0);
    tab[idx * 2]     = (float)cos(f);
    tab[idx * 2 + 1] = (float)sin(f);
}

// ============================================================
// kernel_launch
// ============================================================
extern "C" void kernel_launch(void* const* d_in, const int* in_sizes, int n_in,
                              void* d_out, int out_size, void* d_ws, size_t ws_size,
                              hipStream_t stream)
{
    const float* x      = (const float*)d_in[0];
    const float* qkv_w  = (const float*)d_in[1];
    const float* proj_w = (const float*)d_in[2];
    const float* proj_b = (const float*)d_in[3];
    const float* w1_w   = (const float*)d_in[4];
    const float* w1_b   = (const float*)d_in[5];
    const float* w2_w   = (const float*)d_in[6];
    const float* w2_b   = (const float*)d_in[7];
    const float* w3_w   = (const float*)d_in[8];
    const float* w3_b   = (const float*)d_in[9];
    float* out = (float*)d_out;

    char* ws = (char*)d_ws;
    unsigned short* Qb    = (unsigned short*)(ws);              // [0,16M)
    unsigned short* Kb    = (unsigned short*)(ws + 16777216);   // [16,32M)
    unsigned short* Vtb   = (unsigned short*)(ws + 33554432);   // [32,48M)
    unsigned short* Ob    = (unsigned short*)(ws + 50331648);   // [48,64M)
    unsigned short* out1b = (unsigned short*)(ws + 67108864);   // [64,80M)
    unsigned short* w1b   = (unsigned short*)(ws + 83886080);   // [80,84M)
    unsigned short* w2b   = (unsigned short*)(ws + 88080384);   // [84,88M)
    unsigned short* w3b   = (unsigned short*)(ws + 92274688);   // [88,92M)
    unsigned short* projb = (unsigned short*)(ws + 96468992);   // [92,94M)
    unsigned short* xb    = (unsigned short*)(ws + 98566144);   // [94,110M)
    unsigned short* wqkvb = (unsigned short*)(ws + 115343360);  // [110,116M)
    float*          tab   = (float*)(ws + 121634816);           // [116,116.5M)
    unsigned short* hid   = (unsigned short*)(ws);              // [0,32M)

    const dim3 blk(256);

    // all fp32->bf16 conversions in one dispatch (18874368 elems / 1024)
    cvt_all<<<dim3(18432), blk, 0, stream>>>(
        x, qkv_w, proj_w, w1_w, w2_w, w3_w,
        xb, wqkvb, projb, w1b, w2b, w3b);
    rope_table<<<dim3(256), blk, 0, stream>>>(tab);

    // 1) QKV GEMM + fused rope/scale + coalesced transpose scatter
    mgemm_qkv<<<dim3(24, 64), blk, 0, stream>>>(xb, wqkvb, tab, Qb, Kb, Vtb);
    // 2) MFMA flash attention; grid (bh, qt) -> same-bh blocks co-XCD
    attn_mfma<<<dim3(BATCH * NH, SEQ / 128), blk, 0, stream>>>(Qb, Kb, Vtb, Ob);
    // 3) out1b = Ob @ projb^T + proj_b (bf16)
    mgemm<1, true><<<dim3(8, 64), blk, 0, stream>>>(
        Ob, projb, proj_b, out1b, CDIM, CDIM);
    // 4) hid = silu(out1b@w1^T + b1) * (out1b@w2^T + b2)  [fused, no x2]
    mgemm_glu<<<dim3(32, 64), blk, 0, stream>>>(
        out1b, w1b, w2b, w1_b, w2_b, hid, 2048, CDIM);
    // 5) out = hid @ w3b^T + w3_b (fp32 -> d_out)
    mgemm<0, true><<<dim3(8, 64), blk, 0, stream>>>(
        hid, w3b, w3_b, out, CDIM, 2048);
}

// Round 9
// 474.991 us; speedup vs baseline: 1.2144x; 1.0073x over previous
//
#include <hip/hip_runtime.h>
#include <hip/hip_bf16.h>
#include <math.h>

// ---------------------------------------------------------------------------
// Round 18. R17 (tri-buffer vmcnt(4)) was NULL vs R15 (478.5 vs 479.9;
// qkv 104.9 vs 99.6) -> deeper prefetch isn't the lever on this structure.
// Changes:
//  1) GEMMs reverted to the R15 2-phase double-buffer (proven best).
//  2) T2-style LDS swizzle compatible with gld16 (rule #21): linear LDS
//     dest + PRE-SWIZZLED global source col scol=8*((lane&3)^((lane>>3)&3))
//     + swizzled frag read quad' = quad ^ ((l16>>1)&3). Spreads each
//     16-row slab's frag-read banks (counter: 6.75M conflicts on qkv).
// Pre-committed read: conflicts must collapse; if dur flat anyway, the
// m252 regime-gate transfers and R19 is the 8-phase 256^2 port.
// attn v4 / cvt_all / fast-silu proven, unchanged.
// ---------------------------------------------------------------------------

#define SEQ     2048
#define BATCH   4
#define NH      16
#define CDIM    1024
#define MROWS   8192

typedef __bf16 bf16x8 __attribute__((ext_vector_type(8)));
typedef float  floatx4 __attribute__((ext_vector_type(4)));
typedef float  floatx16 __attribute__((ext_vector_type(16)));
typedef unsigned int u32;

__device__ __forceinline__ unsigned short f2bf(float f) {
    __bf16 h = (__bf16)f;                      // RNE, HW cvt on gfx950
    return __builtin_bit_cast(unsigned short, h);
}
__device__ __forceinline__ float fexp2(float x) {   // 2^x
    float r; asm("v_exp_f32 %0, %1" : "=v"(r) : "v"(x)); return r;
}
__device__ __forceinline__ float frcp(float x) {    // ~1ulp 1/x
    float r; asm("v_rcp_f32 %0, %1" : "=v"(r) : "v"(x)); return r;
}
__device__ __forceinline__ u32 cvtpk(float lo, float hi) {  // 2xbf16 word
    u32 w; asm("v_cvt_pk_bf16_f32 %0, %1, %2" : "=v"(w) : "v"(lo), "v"(hi));
    return w;
}
__device__ __forceinline__ floatx4 mfma16(bf16x8 a, bf16x8 b, floatx4 c) {
    return __builtin_amdgcn_mfma_f32_16x16x32_bf16(a, b, c, 0, 0, 0);
}
__device__ __forceinline__ floatx16 mfma32(bf16x8 a, bf16x8 b, floatx16 c) {
    return __builtin_amdgcn_mfma_f32_32x32x16_bf16(a, b, c, 0, 0, 0);
}
// async global->LDS, 16B/lane; LDS dest wave-uniform base + lane*16
__device__ __forceinline__ void gld16(void* lds, const void* g) {
    __builtin_amdgcn_global_load_lds(
        (const __attribute__((address_space(1))) u32*)g,
        (__attribute__((address_space(3))) u32*)lds, 16, 0, 0);
}
// counted-wait + raw barrier (no compiler vmcnt(0) drain at sync)
__device__ __forceinline__ void wait_vm0_barrier() {
    asm volatile("s_waitcnt vmcnt(0)" ::: "memory");
    __builtin_amdgcn_s_barrier();
    __builtin_amdgcn_sched_barrier(0);
}
__device__ __forceinline__ void raw_barrier() {
    __builtin_amdgcn_s_barrier();
    __builtin_amdgcn_sched_barrier(0);
}

// ============================================================
// bf16 MFMA GEMM NT, 2-phase dbuf + slab swizzle:
// C[m,n] = sum_k A[m,k]*B[n,k] (+bias)
// ============================================================
template <int OUTMODE, bool BIAS>
__global__ __launch_bounds__(256) void mgemm(
    const unsigned short* __restrict__ A,
    const unsigned short* __restrict__ B,
    const float* __restrict__ bias,
    void* __restrict__ C, int ldc,
    int K)
{
    __shared__ __align__(16) unsigned short As[2][128 * 32];
    __shared__ __align__(16) unsigned short Bs[2][128 * 32];

    const int tid  = threadIdx.x;
    const int lane = tid & 63;
    const int wave = tid >> 6;
    const int l16  = lane & 15;
    const int quad = lane >> 4;
    const int wm = (wave >> 1) * 64, wn = (wave & 1) * 64;
    const int bm = blockIdx.y, bn = blockIdx.x;

    const unsigned short* Ag = A + (size_t)(bm * 128) * K;
    const unsigned short* Bg = B + (size_t)(bn * 128) * K;

    // staging: wave w call j fills 16-row slab (w*2+j); lane (r=lane>>2,
    // slot=lane&3) writes LDS linearly but fetches global slot^key(r),
    // key(r) = (r>>1)&3 -> LDS slot s holds global slot s^key(r).
    const int srow0 = wave * 32 + (lane >> 2);
    const int scol  = 8 * ((lane & 3) ^ ((lane >> 3) & 3));
    const unsigned short* gA0 = Ag + (size_t)srow0 * K + scol;
    const unsigned short* gA1 = Ag + (size_t)(srow0 + 16) * K + scol;
    const unsigned short* gB0 = Bg + (size_t)srow0 * K + scol;
    const unsigned short* gB1 = Bg + (size_t)(srow0 + 16) * K + scol;

    auto stage = [&](int b, int kt) {
        gld16(&As[b][(wave * 2 + 0) * 512], gA0 + kt);
        gld16(&As[b][(wave * 2 + 1) * 512], gA1 + kt);
        gld16(&Bs[b][(wave * 2 + 0) * 512], gB0 + kt);
        gld16(&Bs[b][(wave * 2 + 1) * 512], gB1 + kt);
    };

    // frag read: slab-local row = l16, want k-quad 'quad' -> LDS slot
    // quad ^ key(l16)
    const int qsw = (quad ^ ((l16 >> 1) & 3)) * 8;

    floatx4 acc[4][4] = {};
    const int NK = K >> 5;

    stage(0, 0);
    wait_vm0_barrier();

    for (int i = 0; i < NK; ++i) {
        const int cur = i & 1;
        if (i + 1 < NK) stage(cur ^ 1, (i + 1) * 32);

        bf16x8 af[4], bfr[4];
        #pragma unroll
        for (int mt = 0; mt < 4; ++mt)
            af[mt] = *(const bf16x8*)&As[cur][(wm + mt * 16 + l16) * 32 + qsw];
        #pragma unroll
        for (int nt = 0; nt < 4; ++nt)
            bfr[nt] = *(const bf16x8*)&Bs[cur][(wn + nt * 16 + l16) * 32 + qsw];
        #pragma unroll
        for (int mt = 0; mt < 4; ++mt)
            #pragma unroll
            for (int nt = 0; nt < 4; ++nt)
                acc[mt][nt] = mfma16(af[mt], bfr[nt], acc[mt][nt]);

        if (i + 1 < NK) wait_vm0_barrier();
        else            raw_barrier();
    }

    #pragma unroll
    for (int nt = 0; nt < 4; ++nt) {
        const int gcol = bn * 128 + wn + nt * 16 + l16;
        const float bv = BIAS ? bias[gcol] : 0.0f;
        #pragma unroll
        for (int mt = 0; mt < 4; ++mt) {
            #pragma unroll
            for (int r = 0; r < 4; ++r) {
                const int grow = bm * 128 + wm + mt * 16 + quad * 4 + r;
                float v = acc[mt][nt][r] + bv;
                if (OUTMODE == 0)
                    ((float*)C)[(size_t)grow * ldc + gcol] = v;
                else
                    ((unsigned short*)C)[(size_t)grow * ldc + gcol] = f2bf(v);
            }
        }
    }
}

// ============================================================
// Fused SwiGLU GEMM, 128x64 N-tile, 2-phase dbuf + swizzle + fast silu:
// hid[m,n] = silu(A@W1^T + b1) * (A@W2^T + b2)
// ============================================================
__global__ __launch_bounds__(256) void mgemm_glu(
    const unsigned short* __restrict__ A,
    const unsigned short* __restrict__ B1,
    const unsigned short* __restrict__ B2,
    const float* __restrict__ bias1,
    const float* __restrict__ bias2,
    unsigned short* __restrict__ C, int ldc,
    int K)
{
    __shared__ __align__(16) unsigned short As[2][128 * 32];
    __shared__ __align__(16) unsigned short B1s[2][64 * 32];
    __shared__ __align__(16) unsigned short B2s[2][64 * 32];

    const int tid  = threadIdx.x;
    const int lane = tid & 63;
    const int wave = tid >> 6;
    const int l16  = lane & 15;
    const int quad = lane >> 4;
    const int wm = (wave >> 1) * 64, wn = (wave & 1) * 32;
    const int bm = blockIdx.y, bn = blockIdx.x;

    const unsigned short* Ag  = A  + (size_t)(bm * 128) * K;
    const unsigned short* B1g = B1 + (size_t)(bn * 64) * K;
    const unsigned short* B2g = B2 + (size_t)(bn * 64) * K;

    const int arow = wave * 32 + (lane >> 2);
    const int brow = wave * 16 + (lane >> 2);
    const int scol = 8 * ((lane & 3) ^ ((lane >> 3) & 3));
    const unsigned short* gA0 = Ag  + (size_t)arow * K + scol;
    const unsigned short* gA1 = Ag  + (size_t)(arow + 16) * K + scol;
    const unsigned short* gB1 = B1g + (size_t)brow * K + scol;
    const unsigned short* gB2 = B2g + (size_t)brow * K + scol;

    auto stage = [&](int b, int kt) {
        gld16(&As[b][(wave * 2 + 0) * 512], gA0 + kt);
        gld16(&As[b][(wave * 2 + 1) * 512], gA1 + kt);
        gld16(&B1s[b][wave * 512], gB1 + kt);
        gld16(&B2s[b][wave * 512], gB2 + kt);
    };

    const int qsw = (quad ^ ((l16 >> 1) & 3)) * 8;

    floatx4 acc1[4][2] = {};
    floatx4 acc2[4][2] = {};
    const int NK = K >> 5;

    stage(0, 0);
    wait_vm0_barrier();

    for (int i = 0; i < NK; ++i) {
        const int cur = i & 1;
        if (i + 1 < NK) stage(cur ^ 1, (i + 1) * 32);

        bf16x8 af[4], b1f[2], b2f[2];
        #pragma unroll
        for (int mt = 0; mt < 4; ++mt)
            af[mt] = *(const bf16x8*)&As[cur][(wm + mt * 16 + l16) * 32 + qsw];
        #pragma unroll
        for (int nt = 0; nt < 2; ++nt) {
            b1f[nt] = *(const bf16x8*)&B1s[cur][(wn + nt * 16 + l16) * 32 + qsw];
            b2f[nt] = *(const bf16x8*)&B2s[cur][(wn + nt * 16 + l16) * 32 + qsw];
        }
        #pragma unroll
        for (int mt = 0; mt < 4; ++mt)
            #pragma unroll
            for (int nt = 0; nt < 2; ++nt) {
                acc1[mt][nt] = mfma16(af[mt], b1f[nt], acc1[mt][nt]);
                acc2[mt][nt] = mfma16(af[mt], b2f[nt], acc2[mt][nt]);
            }

        if (i + 1 < NK) wait_vm0_barrier();
        else            raw_barrier();
    }

    #pragma unroll
    for (int nt = 0; nt < 2; ++nt) {
        const int gcol = bn * 64 + wn + nt * 16 + l16;
        const float b1 = bias1[gcol];
        const float b2 = bias2[gcol];
        #pragma unroll
        for (int mt = 0; mt < 4; ++mt) {
            #pragma unroll
            for (int r = 0; r < 4; ++r) {
                const int grow = bm * 128 + wm + mt * 16 + quad * 4 + r;
                const float x1 = acc1[mt][nt][r] + b1;
                const float x2 = acc2[mt][nt][r] + b2;
                // silu(x1)*x2 via HW exp2/rcp (log2e folded)
                const float e = fexp2(x1 * -1.44269504088896f);
                const float v = x1 * frcp(1.0f + e) * x2;
                C[(size_t)grow * ldc + gcol] = f2bf(v);
            }
        }
    }
}

// ============================================================
// QKV GEMM, 2-phase dbuf + swizzle, fused epilogues:
//  q/k: fp32 RoPE (table), q pre-scaled by 0.125*log2e, -> Qb/Kb [bh][n][64]
//  v:   LDS-transposed (reuses dead As) -> Vtb [bh][d][n], 16B stores
// ============================================================
__global__ __launch_bounds__(256) void mgemm_qkv(
    const unsigned short* __restrict__ A,
    const unsigned short* __restrict__ B,
    const float* __restrict__ tab,
    unsigned short* __restrict__ Qb,
    unsigned short* __restrict__ Kb,
    unsigned short* __restrict__ Vtb)
{
    __shared__ __align__(16) unsigned short As[2][128 * 32];
    __shared__ __align__(16) unsigned short Bs[2][128 * 32];

    const int tid  = threadIdx.x;
    const int lane = tid & 63;
    const int wave = tid >> 6;
    const int l16  = lane & 15;
    const int quad = lane >> 4;
    const int wm = (wave >> 1) * 64, wn = (wave & 1) * 64;
    const int bm = blockIdx.y, bn = blockIdx.x;
    const int K = CDIM;

    const unsigned short* Ag = A + (size_t)(bm * 128) * K;
    const unsigned short* Bg = B + (size_t)(bn * 128) * K;

    const int srow0 = wave * 32 + (lane >> 2);
    const int scol  = 8 * ((lane & 3) ^ ((lane >> 3) & 3));
    const unsigned short* gA0 = Ag + (size_t)srow0 * K + scol;
    const unsigned short* gA1 = Ag + (size_t)(srow0 + 16) * K + scol;
    const unsigned short* gB0 = Bg + (size_t)srow0 * K + scol;
    const unsigned short* gB1 = Bg + (size_t)(srow0 + 16) * K + scol;

    auto stage = [&](int b, int kt) {
        gld16(&As[b][(wave * 2 + 0) * 512], gA0 + kt);
        gld16(&As[b][(wave * 2 + 1) * 512], gA1 + kt);
        gld16(&Bs[b][(wave * 2 + 0) * 512], gB0 + kt);
        gld16(&Bs[b][(wave * 2 + 1) * 512], gB1 + kt);
    };

    const int qsw = (quad ^ ((l16 >> 1) & 3)) * 8;

    floatx4 acc[4][4] = {};
    const int NK = K >> 5;

    stage(0, 0);
    wait_vm0_barrier();

    for (int i = 0; i < NK; ++i) {
        const int cur = i & 1;
        if (i + 1 < NK) stage(cur ^ 1, (i + 1) * 32);

        bf16x8 af[4], bfr[4];
        #pragma unroll
        for (int mt = 0; mt < 4; ++mt)
            af[mt] = *(const bf16x8*)&As[cur][(wm + mt * 16 + l16) * 32 + qsw];
        #pragma unroll
        for (int nt = 0; nt < 4; ++nt)
            bfr[nt] = *(const bf16x8*)&Bs[cur][(wn + nt * 16 + l16) * 32 + qsw];
        #pragma unroll
        for (int mt = 0; mt < 4; ++mt)
            #pragma unroll
            for (int nt = 0; nt < 4; ++nt)
                acc[mt][nt] = mfma16(af[mt], bfr[nt], acc[mt][nt]);

        if (i + 1 < NK) wait_vm0_barrier();
        else            raw_barrier();
    }

    // part is BLOCK-uniform: 128-col blocks never straddle a 1024 boundary.
    const int colbase0 = bn * 128;
    const int part = colbase0 >> 10;            // 0=q 1=k 2=v

    if (part == 2) {
        // ---- V: transpose via LDS (As dead), write Vtb [bh][d][n] ----
        unsigned short* T = &As[0][0];          // 4 waves x 64d x 16n ushorts
        #pragma unroll
        for (int mt = 0; mt < 4; ++mt) {
            __syncthreads();
            #pragma unroll
            for (int nt = 0; nt < 4; ++nt) {
                ushort4 pk;
                pk.x = f2bf(acc[mt][nt][0]); pk.y = f2bf(acc[mt][nt][1]);
                pk.z = f2bf(acc[mt][nt][2]); pk.w = f2bf(acc[mt][nt][3]);
                *(ushort4*)&T[((wave * 64 + nt * 16 + l16) * 16) + quad * 4] = pk;
            }
            __syncthreads();
            // 256 threads: w2 = tid>>6 (wave-tile), d = tid&63; 32B per thread
            const int w2 = tid >> 6, d = tid & 63;
            const int nrow0 = bm * 128 + (w2 >> 1) * 64 + mt * 16;
            const int b = nrow0 >> 11, n0 = nrow0 & 2047;
            const int h2 = ((bn * 128 + (w2 & 1) * 64) & 1023) >> 6;
            unsigned short* dst = Vtb +
                ((size_t)(b * NH + h2) * 64 + d) * 2048 + n0;
            const int tb = (w2 * 64 + d) * 16;
            *(uint4*)dst       = *(const uint4*)&T[tb];
            *(uint4*)(dst + 8) = *(const uint4*)&T[tb + 8];
        }
    } else {
        // ---- q/k: fp32 RoPE; q scaled by 0.125*log2e (exp2 softmax) ----
        const float qscale = (part == 0) ? 0.125f * 1.44269504088896f : 1.0f;
        const int h = ((colbase0 + wn) & 1023) >> 6;
        #pragma unroll
        for (int mt = 0; mt < 4; ++mt) {
            #pragma unroll
            for (int r = 0; r < 4; ++r) {
                const int grow = bm * 128 + wm + mt * 16 + quad * 4 + r;
                const int b = grow >> 11, n = grow & 2047;
                unsigned short* dst =
                    (part == 0 ? Qb : Kb) + ((size_t)(b * NH + h) * 2048 + n) * 64;
                #pragma unroll
                for (int nt = 0; nt < 2; ++nt) {
                    const int i = nt * 16 + l16;          // 0..31
                    const float c  = tab[(n * 32 + i) * 2];
                    const float sn = tab[(n * 32 + i) * 2 + 1];
                    const float x1 = acc[mt][nt][r];
                    const float x2v = acc[mt][nt + 2][r];
                    dst[i]      = f2bf((x1 * c - x2v * sn) * qscale);
                    dst[i + 32] = f2bf((x2v * c + x1 * sn) * qscale);
                }
            }
        }
    }
}

// ============================================================
// MFMA flash attention v4 (PROVEN R14/R15): 128q blocks, 32x32x16,
// P in registers via cvt_pk + permlane32_swap. Grid (bh, qt).
// ============================================================
__global__ __launch_bounds__(256) void attn_mfma(
    const unsigned short* __restrict__ Qb,
    const unsigned short* __restrict__ Kb,
    const unsigned short* __restrict__ Vtb,
    unsigned short* __restrict__ Ob)
{
    const int bh = blockIdx.x;        // 0..63  (x-major: same-bh -> same XCD)
    const int qt = blockIdx.y;        // 0..15
    const int tid = threadIdx.x;
    const int lane = tid & 63, wave = tid >> 6;
    const int r32 = lane & 31, hi = lane >> 5;
    const int qrow = wave * 32 + r32; // this lane's query row in LDS

    __shared__ unsigned short QP[128][72];  // Q staging (held all iters)
    __shared__ unsigned short Ks[64][72];   // K tile [key][dim]
    __shared__ unsigned short Vs[64][72];   // V^T tile [dim][key]

    const unsigned short* Qg = Qb + ((size_t)bh * 2048 + qt * 128) * 64;
    const unsigned short* Kg = Kb + (size_t)bh * 2048 * 64;
    const unsigned short* Vg = Vtb + (size_t)bh * 64 * 2048;

    // stage Q tile 128x64
    #pragma unroll
    for (int rep = 0; rep < 4; ++rep) {
        const int c = tid + rep * 256;
        const int r = c >> 3, d0 = (c & 7) * 8;
        *(uint4*)&QP[r][d0] = *(const uint4*)(Qg + (size_t)r * 64 + d0);
    }

    // K/V staging slots for this thread (2 b128 each per tile)
    const int c0 = tid, c1 = tid + 256;
    const int kr0 = c0 >> 3, kd0 = (c0 & 7) * 8;
    const int kr1 = c1 >> 3, kd1 = (c1 & 7) * 8;

    // T14 prefetch tile 0 into regs
    uint4 ka0 = *(const uint4*)(Kg + (size_t)kr0 * 64 + kd0);
    uint4 ka1 = *(const uint4*)(Kg + (size_t)kr1 * 64 + kd1);
    uint4 va0 = *(const uint4*)(Vg + (size_t)kr0 * 2048 + kd0);
    uint4 va1 = *(const uint4*)(Vg + (size_t)kr1 * 2048 + kd1);

    __syncthreads();   // Q tile ready

    // Q B-frags (rows = wave's 32 queries), held for all iterations
    bf16x8 bq[4];
    #pragma unroll
    for (int f = 0; f < 4; ++f)
        bq[f] = *(const bf16x8*)&QP[qrow][f * 16 + hi * 8];

    floatx16 o0 = {}, o1 = {};      // O^T[d][q]: d-tiles 0..31 / 32..63
    float l_acc = 0.0f;

    for (int kt = 0; kt < 32; ++kt) {
        __syncthreads();   // prev tile's Ks/Vs frag reads complete
        *(uint4*)&Ks[kr0][kd0] = ka0;
        *(uint4*)&Ks[kr1][kd1] = ka1;
        *(uint4*)&Vs[kr0][kd0] = va0;
        *(uint4*)&Vs[kr1][kd1] = va1;
        if (kt + 1 < 32) {           // T14: issue next-tile loads now,
            const size_t nb = (size_t)(kt + 1) * 64;     // land during compute
            ka0 = *(const uint4*)(Kg + (nb + kr0) * 64 + kd0);
            ka1 = *(const uint4*)(Kg + (nb + kr1) * 64 + kd1);
            va0 = *(const uint4*)(Vg + (size_t)kr0 * 2048 + nb + kd0);
            va1 = *(const uint4*)(Vg + (size_t)kr1 * 2048 + nb + kd1);
        }
        __syncthreads();   // tile ready

        // ---- per 32-key subtile: S^T -> exp2 -> in-reg P -> PV ----
        #pragma unroll
        for (int t = 0; t < 2; ++t) {
            floatx16 s = {};
            #pragma unroll
            for (int f = 0; f < 4; ++f) {
                const bf16x8 ak = *(const bf16x8*)&Ks[t * 32 + r32][f * 16 + hi * 8];
                s = mfma32(ak, bq[f], s);
            }
            // p = exp2(s); rowsum
            float p[16];
            float rs = 0.0f;
            #pragma unroll
            for (int g = 0; g < 16; ++g) { p[g] = fexp2(s[g]); rs += p[g]; }
            l_acc += rs;
            // pack to bf16 words and swap halves across hi
            u32 w0 = cvtpk(p[0], p[1]),   w2 = cvtpk(p[4], p[5]);
            u32 w1 = cvtpk(p[2], p[3]),   w3 = cvtpk(p[6], p[7]);
            u32 w4 = cvtpk(p[8], p[9]),   w6 = cvtpk(p[12], p[13]);
            u32 w5 = cvtpk(p[10], p[11]), w7 = cvtpk(p[14], p[15]);
            asm("v_permlane32_swap_b32 %0, %1" : "+v"(w0), "+v"(w2));
            asm("v_permlane32_swap_b32 %0, %1" : "+v"(w1), "+v"(w3));
            asm("v_permlane32_swap_b32 %0, %1" : "+v"(w4), "+v"(w6));
            asm("v_permlane32_swap_b32 %0, %1" : "+v"(w5), "+v"(w7));
            uint4 u0; u0.x = w0; u0.y = w1; u0.z = w2; u0.w = w3;
            uint4 u1; u1.x = w4; u1.y = w5; u1.z = w6; u1.w = w7;
            const bf16x8 bp0 = __builtin_bit_cast(bf16x8, u0);  // keys t*32 + slot0
            const bf16x8 bp1 = __builtin_bit_cast(bf16x8, u1);  // keys t*32 + slot1
            // PV for this subtile's two 16-key slots (f = 2t, 2t+1)
            {
                const int f0 = 2 * t, f1 = 2 * t + 1;
                const bf16x8 av00 = *(const bf16x8*)&Vs[r32][f0 * 16 + hi * 8];
                const bf16x8 av01 = *(const bf16x8*)&Vs[32 + r32][f0 * 16 + hi * 8];
                o0 = mfma32(av00, bp0, o0);
                o1 = mfma32(av01, bp0, o1);
                const bf16x8 av10 = *(const bf16x8*)&Vs[r32][f1 * 16 + hi * 8];
                const bf16x8 av11 = *(const bf16x8*)&Vs[32 + r32][f1 * 16 + hi * 8];
                o0 = mfma32(av10, bp1, o0);
                o1 = mfma32(av11, bp1, o1);
            }
        }
    }

    // epilogue: lane's query = wave*32 + r32; lanes l/l+32 hold disjoint key
    // halves of the same query -> one shfl to complete l.
    const float l_tot = l_acc + __shfl_xor(l_acc, 32);
    const float inv = 1.0f / l_tot;
    const int b = bh >> 4, h = bh & 15;
    unsigned short* orow = Ob +
        (size_t)(b * SEQ + qt * 128 + qrow) * CDIM + h * 64;
    #pragma unroll
    for (int u = 0; u < 2; ++u) {
        const floatx16 ov = u ? o1 : o0;
        #pragma unroll
        for (int g = 0; g < 4; ++g) {
            ushort4 pk;
            pk.x = f2bf(ov[4 * g + 0] * inv); pk.y = f2bf(ov[4 * g + 1] * inv);
            pk.z = f2bf(ov[4 * g + 2] * inv); pk.w = f2bf(ov[4 * g + 3] * inv);
            // d = u*32 + 8g + 4*hi + (0..3)
            *(ushort4*)(orow + u * 32 + 8 * g + 4 * hi) = pk;
        }
    }
}

// ============================================================
// One-shot fp32 -> bf16 for all six tensors (block-uniform segments);
// RoPE table (fp64 angles)
// ============================================================
__global__ __launch_bounds__(256) void cvt_all(
    const float* __restrict__ x,    const float* __restrict__ qkv,
    const float* __restrict__ proj, const float* __restrict__ w1,
    const float* __restrict__ w2,   const float* __restrict__ w3,
    unsigned short* __restrict__ xb,    unsigned short* __restrict__ qkvb,
    unsigned short* __restrict__ projb, unsigned short* __restrict__ w1b,
    unsigned short* __restrict__ w2b,   unsigned short* __restrict__ w3b)
{
    const size_t i = ((size_t)blockIdx.x * 256 + threadIdx.x) * 4;
    const float* src; unsigned short* dst; size_t off;
    if      (i <  8388608) { src = x;    dst = xb;    off = 0; }
    else if (i < 11534336) { src = qkv;  dst = qkvb;  off = 8388608; }
    else if (i < 12582912) { src = proj; dst = projb; off = 11534336; }
    else if (i < 14680064) { src = w1;   dst = w1b;   off = 12582912; }
    else if (i < 16777216) { src = w2;   dst = w2b;   off = 14680064; }
    else                   { src = w3;   dst = w3b;   off = 16777216; }
    const size_t j = i - off;
    const float4 f = *(const float4*)(src + j);
    ushort4 o; o.x = f2bf(f.x); o.y = f2bf(f.y); o.z = f2bf(f.z); o.w = f2bf(f.w);
    *(ushort4*)(dst + j) = o;
}

__global__ __launch_bounds__(256) void rope_table(float* __restrict__ tab)
{
    const int idx = blockIdx.x * 256 + threadIdx.x;   // < 65536
    const int i = idx & 31, n = idx >> 5;
    const double f = (double)n * pow(10000.0, -(double)(2 * i) / 64.0);
    tab[idx * 2]     = (float)cos(f);
    tab[idx * 2 + 1] = (float)sin(f);
}

// ============================================================
// kernel_launch
// ============================================================
extern "C" void kernel_launch(void* const* d_in, const int* in_sizes, int n_in,
                              void* d_out, int out_size, void* d_ws, size_t ws_size,
                              hipStream_t stream)
{
    const float* x      = (const float*)d_in[0];
    const float* qkv_w  = (const float*)d_in[1];
    const float* proj_w = (const float*)d_in[2];
    const float* proj_b = (const float*)d_in[3];
    const float* w1_w   = (const float*)d_in[4];
    const float* w1_b   = (const float*)d_in[5];
    const float* w2_w   = (const float*)d_in[6];
    const float* w2_b   = (const float*)d_in[7];
    const float* w3_w   = (const float*)d_in[8];
    const float* w3_b   = (const float*)d_in[9];
    float* out = (float*)d_out;

    char* ws = (char*)d_ws;
    unsigned short* Qb    = (unsigned short*)(ws);              // [0,16M)
    unsigned short* Kb    = (unsigned short*)(ws + 16777216);   // [16,32M)
    unsigned short* Vtb   = (unsigned short*)(ws + 33554432);   // [32,48M)
    unsigned short* Ob    = (unsigned short*)(ws + 50331648);   // [48,64M)
    unsigned short* out1b = (unsigned short*)(ws + 67108864);   // [64,80M)
    unsigned short* w1b   = (unsigned short*)(ws + 83886080);   // [80,84M)
    unsigned short* w2b   = (unsigned short*)(ws + 88080384);   // [84,88M)
    unsigned short* w3b   = (unsigned short*)(ws + 92274688);   // [88,92M)
    unsigned short* projb = (unsigned short*)(ws + 96468992);   // [92,94M)
    unsigned short* xb    = (unsigned short*)(ws + 98566144);   // [94,110M)
    unsigned short* wqkvb = (unsigned short*)(ws + 115343360);  // [110,116M)
    float*          tab   = (float*)(ws + 121634816);           // [116,116.5M)
    unsigned short* hid   = (unsigned short*)(ws);              // [0,32M)

    const dim3 blk(256);

    // all fp32->bf16 conversions in one dispatch (18874368 elems / 1024)
    cvt_all<<<dim3(18432), blk, 0, stream>>>(
        x, qkv_w, proj_w, w1_w, w2_w, w3_w,
        xb, wqkvb, projb, w1b, w2b, w3b);
    rope_table<<<dim3(256), blk, 0, stream>>>(tab);

    // 1) QKV GEMM + fused rope/scale + coalesced transpose scatter
    mgemm_qkv<<<dim3(24, 64), blk, 0, stream>>>(xb, wqkvb, tab, Qb, Kb, Vtb);
    // 2) MFMA flash attention; grid (bh, qt) -> same-bh blocks co-XCD
    attn_mfma<<<dim3(BATCH * NH, SEQ / 128), blk, 0, stream>>>(Qb, Kb, Vtb, Ob);
    // 3) out1b = Ob @ projb^T + proj_b (bf16)
    mgemm<1, true><<<dim3(8, 64), blk, 0, stream>>>(
        Ob, projb, proj_b, out1b, CDIM, CDIM);
    // 4) hid = silu(out1b@w1^T + b1) * (out1b@w2^T + b2)  [fused, no x2]
    mgemm_glu<<<dim3(32, 64), blk, 0, stream>>>(
        out1b, w1b, w2b, w1_b, w2_b, hid, 2048, CDIM);
    // 5) out = hid @ w3b^T + w3_b (fp32 -> d_out)
    mgemm<0, true><<<dim3(8, 64), blk, 0, stream>>>(
        hid, w3b, w3_b, out, CDIM, 2048);
}

// Round 10
// 443.286 us; speedup vs baseline: 1.3012x; 1.0715x over previous
//
#include <hip/hip_runtime.h>
#include <hip/hip_bf16.h>
#include <math.h>

// ---------------------------------------------------------------------------
// Round 19. R18: swizzle killed conflicts 6.75M->459K but dur flat ->
// m252 regime-gate confirmed: 2-phase loop is stage+barrier-bound; the
// proven escape is the 8-phase 256^2 schedule (T3+T4+T5, learn_hip m201).
// Change: mgemm_qkv ported to 8-phase 256^2 (512 thr, 128KB LDS dbuf,
// BK=64, per-wave 128x64, counted vmcnt(2) at K-tile boundaries only,
// setprio around MFMA clusters, swizzled staging/reads as validated R18).
// Epilogues (RoPE, V-transpose) remapped to the 2x4 wave grid.
// mgemm / mgemm_glu / attn / cvt_all unchanged (R18-proven, 475.0us).
// ---------------------------------------------------------------------------

#define SEQ     2048
#define BATCH   4
#define NH      16
#define CDIM    1024
#define MROWS   8192

typedef __bf16 bf16x8 __attribute__((ext_vector_type(8)));
typedef float  floatx4 __attribute__((ext_vector_type(4)));
typedef float  floatx16 __attribute__((ext_vector_type(16)));
typedef unsigned int u32;

__device__ __forceinline__ unsigned short f2bf(float f) {
    __bf16 h = (__bf16)f;                      // RNE, HW cvt on gfx950
    return __builtin_bit_cast(unsigned short, h);
}
__device__ __forceinline__ float fexp2(float x) {   // 2^x
    float r; asm("v_exp_f32 %0, %1" : "=v"(r) : "v"(x)); return r;
}
__device__ __forceinline__ float frcp(float x) {    // ~1ulp 1/x
    float r; asm("v_rcp_f32 %0, %1" : "=v"(r) : "v"(x)); return r;
}
__device__ __forceinline__ u32 cvtpk(float lo, float hi) {  // 2xbf16 word
    u32 w; asm("v_cvt_pk_bf16_f32 %0, %1, %2" : "=v"(w) : "v"(lo), "v"(hi));
    return w;
}
__device__ __forceinline__ floatx4 mfma16(bf16x8 a, bf16x8 b, floatx4 c) {
    return __builtin_amdgcn_mfma_f32_16x16x32_bf16(a, b, c, 0, 0, 0);
}
__device__ __forceinline__ floatx16 mfma32(bf16x8 a, bf16x8 b, floatx16 c) {
    return __builtin_amdgcn_mfma_f32_32x32x16_bf16(a, b, c, 0, 0, 0);
}
// async global->LDS, 16B/lane; LDS dest wave-uniform base + lane*16
__device__ __forceinline__ void gld16(void* lds, const void* g) {
    __builtin_amdgcn_global_load_lds(
        (const __attribute__((address_space(1))) u32*)g,
        (__attribute__((address_space(3))) u32*)lds, 16, 0, 0);
}
// counted-wait + raw barrier (no compiler vmcnt(0) drain at sync)
__device__ __forceinline__ void wait_vm0_barrier() {
    asm volatile("s_waitcnt vmcnt(0)" ::: "memory");
    __builtin_amdgcn_s_barrier();
    __builtin_amdgcn_sched_barrier(0);
}
__device__ __forceinline__ void raw_barrier() {
    __builtin_amdgcn_s_barrier();
    __builtin_amdgcn_sched_barrier(0);
}

// ============================================================
// bf16 MFMA GEMM NT, 2-phase dbuf + slab swizzle (R18-proven):
// C[m,n] = sum_k A[m,k]*B[n,k] (+bias)
// ============================================================
template <int OUTMODE, bool BIAS>
__global__ __launch_bounds__(256) void mgemm(
    const unsigned short* __restrict__ A,
    const unsigned short* __restrict__ B,
    const float* __restrict__ bias,
    void* __restrict__ C, int ldc,
    int K)
{
    __shared__ __align__(16) unsigned short As[2][128 * 32];
    __shared__ __align__(16) unsigned short Bs[2][128 * 32];

    const int tid  = threadIdx.x;
    const int lane = tid & 63;
    const int wave = tid >> 6;
    const int l16  = lane & 15;
    const int quad = lane >> 4;
    const int wm = (wave >> 1) * 64, wn = (wave & 1) * 64;
    const int bm = blockIdx.y, bn = blockIdx.x;

    const unsigned short* Ag = A + (size_t)(bm * 128) * K;
    const unsigned short* Bg = B + (size_t)(bn * 128) * K;

    const int srow0 = wave * 32 + (lane >> 2);
    const int scol  = 8 * ((lane & 3) ^ ((lane >> 3) & 3));
    const unsigned short* gA0 = Ag + (size_t)srow0 * K + scol;
    const unsigned short* gA1 = Ag + (size_t)(srow0 + 16) * K + scol;
    const unsigned short* gB0 = Bg + (size_t)srow0 * K + scol;
    const unsigned short* gB1 = Bg + (size_t)(srow0 + 16) * K + scol;

    auto stage = [&](int b, int kt) {
        gld16(&As[b][(wave * 2 + 0) * 512], gA0 + kt);
        gld16(&As[b][(wave * 2 + 1) * 512], gA1 + kt);
        gld16(&Bs[b][(wave * 2 + 0) * 512], gB0 + kt);
        gld16(&Bs[b][(wave * 2 + 1) * 512], gB1 + kt);
    };

    const int qsw = (quad ^ ((l16 >> 1) & 3)) * 8;

    floatx4 acc[4][4] = {};
    const int NK = K >> 5;

    stage(0, 0);
    wait_vm0_barrier();

    for (int i = 0; i < NK; ++i) {
        const int cur = i & 1;
        if (i + 1 < NK) stage(cur ^ 1, (i + 1) * 32);

        bf16x8 af[4], bfr[4];
        #pragma unroll
        for (int mt = 0; mt < 4; ++mt)
            af[mt] = *(const bf16x8*)&As[cur][(wm + mt * 16 + l16) * 32 + qsw];
        #pragma unroll
        for (int nt = 0; nt < 4; ++nt)
            bfr[nt] = *(const bf16x8*)&Bs[cur][(wn + nt * 16 + l16) * 32 + qsw];
        #pragma unroll
        for (int mt = 0; mt < 4; ++mt)
            #pragma unroll
            for (int nt = 0; nt < 4; ++nt)
                acc[mt][nt] = mfma16(af[mt], bfr[nt], acc[mt][nt]);

        if (i + 1 < NK) wait_vm0_barrier();
        else            raw_barrier();
    }

    #pragma unroll
    for (int nt = 0; nt < 4; ++nt) {
        const int gcol = bn * 128 + wn + nt * 16 + l16;
        const float bv = BIAS ? bias[gcol] : 0.0f;
        #pragma unroll
        for (int mt = 0; mt < 4; ++mt) {
            #pragma unroll
            for (int r = 0; r < 4; ++r) {
                const int grow = bm * 128 + wm + mt * 16 + quad * 4 + r;
                float v = acc[mt][nt][r] + bv;
                if (OUTMODE == 0)
                    ((float*)C)[(size_t)grow * ldc + gcol] = v;
                else
                    ((unsigned short*)C)[(size_t)grow * ldc + gcol] = f2bf(v);
            }
        }
    }
}

// ============================================================
// Fused SwiGLU GEMM, 128x64 N-tile (R18-proven):
// hid[m,n] = silu(A@W1^T + b1) * (A@W2^T + b2)
// ============================================================
__global__ __launch_bounds__(256) void mgemm_glu(
    const unsigned short* __restrict__ A,
    const unsigned short* __restrict__ B1,
    const unsigned short* __restrict__ B2,
    const float* __restrict__ bias1,
    const float* __restrict__ bias2,
    unsigned short* __restrict__ C, int ldc,
    int K)
{
    __shared__ __align__(16) unsigned short As[2][128 * 32];
    __shared__ __align__(16) unsigned short B1s[2][64 * 32];
    __shared__ __align__(16) unsigned short B2s[2][64 * 32];

    const int tid  = threadIdx.x;
    const int lane = tid & 63;
    const int wave = tid >> 6;
    const int l16  = lane & 15;
    const int quad = lane >> 4;
    const int wm = (wave >> 1) * 64, wn = (wave & 1) * 32;
    const int bm = blockIdx.y, bn = blockIdx.x;

    const unsigned short* Ag  = A  + (size_t)(bm * 128) * K;
    const unsigned short* B1g = B1 + (size_t)(bn * 64) * K;
    const unsigned short* B2g = B2 + (size_t)(bn * 64) * K;

    const int arow = wave * 32 + (lane >> 2);
    const int brow = wave * 16 + (lane >> 2);
    const int scol = 8 * ((lane & 3) ^ ((lane >> 3) & 3));
    const unsigned short* gA0 = Ag  + (size_t)arow * K + scol;
    const unsigned short* gA1 = Ag  + (size_t)(arow + 16) * K + scol;
    const unsigned short* gB1 = B1g + (size_t)brow * K + scol;
    const unsigned short* gB2 = B2g + (size_t)brow * K + scol;

    auto stage = [&](int b, int kt) {
        gld16(&As[b][(wave * 2 + 0) * 512], gA0 + kt);
        gld16(&As[b][(wave * 2 + 1) * 512], gA1 + kt);
        gld16(&B1s[b][wave * 512], gB1 + kt);
        gld16(&B2s[b][wave * 512], gB2 + kt);
    };

    const int qsw = (quad ^ ((l16 >> 1) & 3)) * 8;

    floatx4 acc1[4][2] = {};
    floatx4 acc2[4][2] = {};
    const int NK = K >> 5;

    stage(0, 0);
    wait_vm0_barrier();

    for (int i = 0; i < NK; ++i) {
        const int cur = i & 1;
        if (i + 1 < NK) stage(cur ^ 1, (i + 1) * 32);

        bf16x8 af[4], b1f[2], b2f[2];
        #pragma unroll
        for (int mt = 0; mt < 4; ++mt)
            af[mt] = *(const bf16x8*)&As[cur][(wm + mt * 16 + l16) * 32 + qsw];
        #pragma unroll
        for (int nt = 0; nt < 2; ++nt) {
            b1f[nt] = *(const bf16x8*)&B1s[cur][(wn + nt * 16 + l16) * 32 + qsw];
            b2f[nt] = *(const bf16x8*)&B2s[cur][(wn + nt * 16 + l16) * 32 + qsw];
        }
        #pragma unroll
        for (int mt = 0; mt < 4; ++mt)
            #pragma unroll
            for (int nt = 0; nt < 2; ++nt) {
                acc1[mt][nt] = mfma16(af[mt], b1f[nt], acc1[mt][nt]);
                acc2[mt][nt] = mfma16(af[mt], b2f[nt], acc2[mt][nt]);
            }

        if (i + 1 < NK) wait_vm0_barrier();
        else            raw_barrier();
    }

    #pragma unroll
    for (int nt = 0; nt < 2; ++nt) {
        const int gcol = bn * 64 + wn + nt * 16 + l16;
        const float b1 = bias1[gcol];
        const float b2 = bias2[gcol];
        #pragma unroll
        for (int mt = 0; mt < 4; ++mt) {
            #pragma unroll
            for (int r = 0; r < 4; ++r) {
                const int grow = bm * 128 + wm + mt * 16 + quad * 4 + r;
                const float x1 = acc1[mt][nt][r] + b1;
                const float x2 = acc2[mt][nt][r] + b2;
                // silu(x1)*x2 via HW exp2/rcp (log2e folded)
                const float e = fexp2(x1 * -1.44269504088896f);
                const float v = x1 * frcp(1.0f + e) * x2;
                C[(size_t)grow * ldc + gcol] = f2bf(v);
            }
        }
    }
}

// ============================================================
// QKV GEMM — 8-phase 256^2 schedule (T3+T4+T5):
// 512 thr / 8 waves (2M x 4N), BK=64, LDS 128KB dbuf, per-wave 128x64.
// Per K-tile: 4 phases x 16 MFMA (C-quadrant mh x nh; A/B frag reuse).
// Per phase: one half-tile stage (2x gld16, pre-swizzled source slot
// (lane&7)^(lane>>3); frag reads use slot quad^(l16&7) -> conflict-free).
// vmcnt(2) ONLY at K-tile boundaries (p3/p7); never 0 mid-loop.
// Staging hazard-checked: each half-tile's overwrite is >=1 barrier
// after its last reader (A-halves last read p2/p6, B-halves p1/p5).
// Epilogues: q/k fp32 RoPE (q pre-scaled 0.125*log2e); v LDS-transpose.
// ============================================================
#define RD_A(buf, mh)                                                     \
    { _Pragma("unroll") for (int i_ = 0; i_ < 4; ++i_) {                  \
        const int ro_ = (arow + ((mh) * 4 + i_) * 16) * 64;               \
        aF[i_][0] = *(const bf16x8*)&As[buf][ro_ + e0];                   \
        aF[i_][1] = *(const bf16x8*)&As[buf][ro_ + e1]; } }

#define RD_B(buf, nh)                                                     \
    { _Pragma("unroll") for (int n_ = 0; n_ < 2; ++n_) {                  \
        const int ro_ = (brow + ((nh) * 2 + n_) * 16) * 64;               \
        bF[nh][n_][0] = *(const bf16x8*)&Bs[buf][ro_ + e0];               \
        bF[nh][n_][1] = *(const bf16x8*)&Bs[buf][ro_ + e1]; } }

#define DO_MFMA(mh, nh)                                                   \
    { _Pragma("unroll") for (int i_ = 0; i_ < 4; ++i_)                    \
      { _Pragma("unroll") for (int n_ = 0; n_ < 2; ++n_) {                \
        acc[(mh)*4+i_][(nh)*2+n_] =                                       \
            mfma16(aF[i_][0], bF[nh][n_][0], acc[(mh)*4+i_][(nh)*2+n_]);  \
        acc[(mh)*4+i_][(nh)*2+n_] =                                       \
            mfma16(aF[i_][1], bF[nh][n_][1], acc[(mh)*4+i_][(nh)*2+n_]);  \
      } } }

#define PH_ENTER()                                                        \
    __builtin_amdgcn_s_barrier();                                         \
    asm volatile("s_waitcnt lgkmcnt(0)" ::: "memory");                    \
    __builtin_amdgcn_sched_barrier(0);                                    \
    __builtin_amdgcn_s_setprio(1)

#define PH_EXIT() __builtin_amdgcn_s_setprio(0)

__global__ __launch_bounds__(512, 2) void mgemm_qkv(
    const unsigned short* __restrict__ A,
    const unsigned short* __restrict__ B,
    const float* __restrict__ tab,
    unsigned short* __restrict__ Qb,
    unsigned short* __restrict__ Kb,
    unsigned short* __restrict__ Vtb)
{
    __shared__ __align__(16) unsigned short As[2][256 * 64];
    __shared__ __align__(16) unsigned short Bs[2][256 * 64];

    const int tid  = threadIdx.x;
    const int lane = tid & 63;
    const int wave = tid >> 6;          // 0..7
    const int l16  = lane & 15;
    const int quad = lane >> 4;
    const int wr   = wave >> 2;         // M half (0..1)
    const int wc   = wave & 3;          // N quarter (0..3)
    const int bn = blockIdx.x, bm = blockIdx.y;
    const int K = CDIM;

    const unsigned short* Ag = A + (size_t)(bm * 256) * K;
    const unsigned short* Bg = B + (size_t)(bn * 256) * K;

    // staging: lane covers row lane>>3 of an 8-row slab, 16B slot lane&7;
    // pre-swizzled source so LDS[row][slot] = global[row][slot^(row&7)]
    const int srow  = lane >> 3;
    const int sgcol = ((lane & 7) ^ srow) * 8;

    auto stA = [&](int buf, int half, int kt) {
        #pragma unroll
        for (int s = 0; s < 2; ++s) {
            const int rbase = half * 128 + (wave * 2 + s) * 8;
            gld16(&As[buf][rbase * 64],
                  Ag + (size_t)(rbase + srow) * K + kt + sgcol);
        }
    };
    auto stB = [&](int buf, int half, int kt) {
        #pragma unroll
        for (int s = 0; s < 2; ++s) {
            const int rbase = half * 128 + (wave * 2 + s) * 8;
            gld16(&Bs[buf][rbase * 64],
                  Bg + (size_t)(rbase + srow) * K + kt + sgcol);
        }
    };

    // frag-read swizzled slot offsets (elements)
    const int e0 = ((quad)     ^ (l16 & 7)) * 8;   // k 0..31
    const int e1 = ((quad + 4) ^ (l16 & 7)) * 8;   // k 32..63
    const int arow = wr * 128 + l16;
    const int brow = wc * 64 + l16;

    floatx4 acc[8][4] = {};
    bf16x8 aF[4][2];
    bf16x8 bF[2][2][2];                 // [nh][n][kh]

    // prologue: KT0 full -> buf0; KT1 A-h0 -> buf1 (10 loads, keep 2 flying)
    stA(0, 0, 0); stA(0, 1, 0); stB(0, 0, 0); stB(0, 1, 0);
    stA(1, 0, 64);
    asm volatile("s_waitcnt vmcnt(2)" ::: "memory");
    __builtin_amdgcn_s_barrier();
    __builtin_amdgcn_sched_barrier(0);

    for (int j = 0; j < 8; ++j) {
        const int k1 = (2 * j + 1) * 64;
        const int k2 = (2 * j + 2) * 64;
        const int k3 = (2 * j + 3) * 64;
        const bool more = (j < 7);

        // p0: buf0 mh0 x nh0; stage buf1 A-h1 @k1
        RD_A(0, 0); RD_B(0, 0);
        stA(1, 1, k1);
        PH_ENTER(); DO_MFMA(0, 0); PH_EXIT();
        __builtin_amdgcn_s_barrier();

        // p1: buf0 mh0 x nh1; stage buf1 B-h0 @k1
        RD_B(0, 1);
        stB(1, 0, k1);
        PH_ENTER(); DO_MFMA(0, 1); PH_EXIT();
        __builtin_amdgcn_s_barrier();

        // p2: buf0 mh1 x nh1; stage buf1 B-h1 @k1
        RD_A(0, 1);
        stB(1, 1, k1);
        PH_ENTER(); DO_MFMA(1, 1); PH_EXIT();
        __builtin_amdgcn_s_barrier();

        // p3: buf0 mh1 x nh0 (regs reused); stage buf0 A-h0 @k2; KT boundary
        if (more) stA(0, 0, k2);
        PH_ENTER(); DO_MFMA(1, 0); PH_EXIT();
        if (more) { asm volatile("s_waitcnt vmcnt(2)" ::: "memory"); }
        else      { asm volatile("s_waitcnt vmcnt(0)" ::: "memory"); }
        __builtin_amdgcn_s_barrier();

        // p4: buf1 mh0 x nh0; stage buf0 A-h1 @k2
        RD_A(1, 0); RD_B(1, 0);
        if (more) stA(0, 1, k2);
        PH_ENTER(); DO_MFMA(0, 0); PH_EXIT();
        __builtin_amdgcn_s_barrier();

        // p5: buf1 mh0 x nh1; stage buf0 B-h0 @k2
        RD_B(1, 1);
        if (more) stB(0, 0, k2);
        PH_ENTER(); DO_MFMA(0, 1); PH_EXIT();
        __builtin_amdgcn_s_barrier();

        // p6: buf1 mh1 x nh1; stage buf0 B-h1 @k2
        RD_A(1, 1);
        if (more) stB(0, 1, k2);
        PH_ENTER(); DO_MFMA(1, 1); PH_EXIT();
        __builtin_amdgcn_s_barrier();

        // p7: buf1 mh1 x nh0; stage buf1 A-h0 @k3; KT boundary
        if (more) stA(1, 0, k3);
        PH_ENTER(); DO_MFMA(1, 0); PH_EXIT();
        if (more) {
            asm volatile("s_waitcnt vmcnt(2)" ::: "memory");
            __builtin_amdgcn_s_barrier();
        }
    }

    // ---- epilogues ----
    const int part = bn >> 2;           // 0=q 1=k 2=v (256-col blocks)

    if (part == 2) {
        // V: transpose via LDS (As dead) -> Vtb [bh][d][n], 32B stores
        unsigned short* T = &As[0][0];  // [2][256][16] ushort = 16 KB
        #pragma unroll
        for (int m = 0; m < 8; ++m) {
            __syncthreads();
            #pragma unroll
            for (int n = 0; n < 4; ++n) {
                ushort4 pk;
                pk.x = f2bf(acc[m][n][0]); pk.y = f2bf(acc[m][n][1]);
                pk.z = f2bf(acc[m][n][2]); pk.w = f2bf(acc[m][n][3]);
                *(ushort4*)&T[(wr * 256 + wc * 64 + n * 16 + l16) * 16 + quad * 4] = pk;
            }
            __syncthreads();
            // 512 threads: wr2 = tid>>8, col = tid&255; 32B along n
            const int wr2 = tid >> 8, col = tid & 255;
            const int grow0 = bm * 256 + wr2 * 128 + m * 16;
            const int b = grow0 >> 11, n0 = grow0 & 2047;
            const int h2 = (bn & 3) * 4 + (col >> 6);
            const int d  = col & 63;
            unsigned short* dst = Vtb +
                ((size_t)(b * NH + h2) * 64 + d) * 2048 + n0;
            const int tb = (wr2 * 256 + col) * 16;
            *(uint4*)dst       = *(const uint4*)&T[tb];
            *(uint4*)(dst + 8) = *(const uint4*)&T[tb + 8];
        }
    } else {
        // q/k: fp32 RoPE; q scaled by 0.125*log2e (exp2 softmax)
        const float qscale = (part == 0) ? 0.125f * 1.44269504088896f : 1.0f;
        const int h = (bn & 3) * 4 + wc;
        unsigned short* qk = (part == 0) ? Qb : Kb;
        #pragma unroll
        for (int m = 0; m < 8; ++m) {
            #pragma unroll
            for (int r = 0; r < 4; ++r) {
                const int grow = bm * 256 + wr * 128 + m * 16 + quad * 4 + r;
                const int b = grow >> 11, n = grow & 2047;
                unsigned short* dst = qk + ((size_t)(b * NH + h) * 2048 + n) * 64;
                #pragma unroll
                for (int nt = 0; nt < 2; ++nt) {
                    const int i = nt * 16 + l16;          // 0..31
                    const float c  = tab[(n * 32 + i) * 2];
                    const float sn = tab[(n * 32 + i) * 2 + 1];
                    const float x1  = acc[m][nt][r];
                    const float x2v = acc[m][nt + 2][r];
                    dst[i]      = f2bf((x1 * c - x2v * sn) * qscale);
                    dst[i + 32] = f2bf((x2v * c + x1 * sn) * qscale);
                }
            }
        }
    }
}

// ============================================================
// MFMA flash attention v4 (PROVEN R14/R15): 128q blocks, 32x32x16,
// P in registers via cvt_pk + permlane32_swap. Grid (bh, qt).
// ============================================================
__global__ __launch_bounds__(256) void attn_mfma(
    const unsigned short* __restrict__ Qb,
    const unsigned short* __restrict__ Kb,
    const unsigned short* __restrict__ Vtb,
    unsigned short* __restrict__ Ob)
{
    const int bh = blockIdx.x;        // 0..63  (x-major: same-bh -> same XCD)
    const int qt = blockIdx.y;        // 0..15
    const int tid = threadIdx.x;
    const int lane = tid & 63, wave = tid >> 6;
    const int r32 = lane & 31, hi = lane >> 5;
    const int qrow = wave * 32 + r32; // this lane's query row in LDS

    __shared__ unsigned short QP[128][72];  // Q staging (held all iters)
    __shared__ unsigned short Ks[64][72];   // K tile [key][dim]
    __shared__ unsigned short Vs[64][72];   // V^T tile [dim][key]

    const unsigned short* Qg = Qb + ((size_t)bh * 2048 + qt * 128) * 64;
    const unsigned short* Kg = Kb + (size_t)bh * 2048 * 64;
    const unsigned short* Vg = Vtb + (size_t)bh * 64 * 2048;

    // stage Q tile 128x64
    #pragma unroll
    for (int rep = 0; rep < 4; ++rep) {
        const int c = tid + rep * 256;
        const int r = c >> 3, d0 = (c & 7) * 8;
        *(uint4*)&QP[r][d0] = *(const uint4*)(Qg + (size_t)r * 64 + d0);
    }

    // K/V staging slots for this thread (2 b128 each per tile)
    const int c0 = tid, c1 = tid + 256;
    const int kr0 = c0 >> 3, kd0 = (c0 & 7) * 8;
    const int kr1 = c1 >> 3, kd1 = (c1 & 7) * 8;

    // T14 prefetch tile 0 into regs
    uint4 ka0 = *(const uint4*)(Kg + (size_t)kr0 * 64 + kd0);
    uint4 ka1 = *(const uint4*)(Kg + (size_t)kr1 * 64 + kd1);
    uint4 va0 = *(const uint4*)(Vg + (size_t)kr0 * 2048 + kd0);
    uint4 va1 = *(const uint4*)(Vg + (size_t)kr1 * 2048 + kd1);

    __syncthreads();   // Q tile ready

    // Q B-frags (rows = wave's 32 queries), held for all iterations
    bf16x8 bq[4];
    #pragma unroll
    for (int f = 0; f < 4; ++f)
        bq[f] = *(const bf16x8*)&QP[qrow][f * 16 + hi * 8];

    floatx16 o0 = {}, o1 = {};      // O^T[d][q]: d-tiles 0..31 / 32..63
    float l_acc = 0.0f;

    for (int kt = 0; kt < 32; ++kt) {
        __syncthreads();   // prev tile's Ks/Vs frag reads complete
        *(uint4*)&Ks[kr0][kd0] = ka0;
        *(uint4*)&Ks[kr1][kd1] = ka1;
        *(uint4*)&Vs[kr0][kd0] = va0;
        *(uint4*)&Vs[kr1][kd1] = va1;
        if (kt + 1 < 32) {           // T14: issue next-tile loads now,
            const size_t nb = (size_t)(kt + 1) * 64;     // land during compute
            ka0 = *(const uint4*)(Kg + (nb + kr0) * 64 + kd0);
            ka1 = *(const uint4*)(Kg + (nb + kr1) * 64 + kd1);
            va0 = *(const uint4*)(Vg + (size_t)kr0 * 2048 + nb + kd0);
            va1 = *(const uint4*)(Vg + (size_t)kr1 * 2048 + nb + kd1);
        }
        __syncthreads();   // tile ready

        // ---- per 32-key subtile: S^T -> exp2 -> in-reg P -> PV ----
        #pragma unroll
        for (int t = 0; t < 2; ++t) {
            floatx16 s = {};
            #pragma unroll
            for (int f = 0; f < 4; ++f) {
                const bf16x8 ak = *(const bf16x8*)&Ks[t * 32 + r32][f * 16 + hi * 8];
                s = mfma32(ak, bq[f], s);
            }
            // p = exp2(s); rowsum
            float p[16];
            float rs = 0.0f;
            #pragma unroll
            for (int g = 0; g < 16; ++g) { p[g] = fexp2(s[g]); rs += p[g]; }
            l_acc += rs;
            // pack to bf16 words and swap halves across hi
            u32 w0 = cvtpk(p[0], p[1]),   w2 = cvtpk(p[4], p[5]);
            u32 w1 = cvtpk(p[2], p[3]),   w3 = cvtpk(p[6], p[7]);
            u32 w4 = cvtpk(p[8], p[9]),   w6 = cvtpk(p[12], p[13]);
            u32 w5 = cvtpk(p[10], p[11]), w7 = cvtpk(p[14], p[15]);
            asm("v_permlane32_swap_b32 %0, %1" : "+v"(w0), "+v"(w2));
            asm("v_permlane32_swap_b32 %0, %1" : "+v"(w1), "+v"(w3));
            asm("v_permlane32_swap_b32 %0, %1" : "+v"(w4), "+v"(w6));
            asm("v_permlane32_swap_b32 %0, %1" : "+v"(w5), "+v"(w7));
            uint4 u0; u0.x = w0; u0.y = w1; u0.z = w2; u0.w = w3;
            uint4 u1; u1.x = w4; u1.y = w5; u1.z = w6; u1.w = w7;
            const bf16x8 bp0 = __builtin_bit_cast(bf16x8, u0);  // keys t*32 + slot0
            const bf16x8 bp1 = __builtin_bit_cast(bf16x8, u1);  // keys t*32 + slot1
            // PV for this subtile's two 16-key slots (f = 2t, 2t+1)
            {
                const int f0 = 2 * t, f1 = 2 * t + 1;
                const bf16x8 av00 = *(const bf16x8*)&Vs[r32][f0 * 16 + hi * 8];
                const bf16x8 av01 = *(const bf16x8*)&Vs[32 + r32][f0 * 16 + hi * 8];
                o0 = mfma32(av00, bp0, o0);
                o1 = mfma32(av01, bp0, o1);
                const bf16x8 av10 = *(const bf16x8*)&Vs[r32][f1 * 16 + hi * 8];
                const bf16x8 av11 = *(const bf16x8*)&Vs[32 + r32][f1 * 16 + hi * 8];
                o0 = mfma32(av10, bp1, o0);
                o1 = mfma32(av11, bp1, o1);
            }
        }
    }

    // epilogue: lane's query = wave*32 + r32; lanes l/l+32 hold disjoint key
    // halves of the same query -> one shfl to complete l.
    const float l_tot = l_acc + __shfl_xor(l_acc, 32);
    const float inv = 1.0f / l_tot;
    const int b = bh >> 4, h = bh & 15;
    unsigned short* orow = Ob +
        (size_t)(b * SEQ + qt * 128 + qrow) * CDIM + h * 64;
    #pragma unroll
    for (int u = 0; u < 2; ++u) {
        const floatx16 ov = u ? o1 : o0;
        #pragma unroll
        for (int g = 0; g < 4; ++g) {
            ushort4 pk;
            pk.x = f2bf(ov[4 * g + 0] * inv); pk.y = f2bf(ov[4 * g + 1] * inv);
            pk.z = f2bf(ov[4 * g + 2] * inv); pk.w = f2bf(ov[4 * g + 3] * inv);
            // d = u*32 + 8g + 4*hi + (0..3)
            *(ushort4*)(orow + u * 32 + 8 * g + 4 * hi) = pk;
        }
    }
}

// ============================================================
// One-shot fp32 -> bf16 for all six tensors (block-uniform segments);
// RoPE table (fp64 angles)
// ============================================================
__global__ __launch_bounds__(256) void cvt_all(
    const float* __restrict__ x,    const float* __restrict__ qkv,
    const float* __restrict__ proj, const float* __restrict__ w1,
    const float* __restrict__ w2,   const float* __restrict__ w3,
    unsigned short* __restrict__ xb,    unsigned short* __restrict__ qkvb,
    unsigned short* __restrict__ projb, unsigned short* __restrict__ w1b,
    unsigned short* __restrict__ w2b,   unsigned short* __restrict__ w3b)
{
    const size_t i = ((size_t)blockIdx.x * 256 + threadIdx.x) * 4;
    const float* src; unsigned short* dst; size_t off;
    if      (i <  8388608) { src = x;    dst = xb;    off = 0; }
    else if (i < 11534336) { src = qkv;  dst = qkvb;  off = 8388608; }
    else if (i < 12582912) { src = proj; dst = projb; off = 11534336; }
    else if (i < 14680064) { src = w1;   dst = w1b;   off = 12582912; }
    else if (i < 16777216) { src = w2;   dst = w2b;   off = 14680064; }
    else                   { src = w3;   dst = w3b;   off = 16777216; }
    const size_t j = i - off;
    const float4 f = *(const float4*)(src + j);
    ushort4 o; o.x = f2bf(f.x); o.y = f2bf(f.y); o.z = f2bf(f.z); o.w = f2bf(f.w);
    *(ushort4*)(dst + j) = o;
}

__global__ __launch_bounds__(256) void rope_table(float* __restrict__ tab)
{
    const int idx = blockIdx.x * 256 + threadIdx.x;   // < 65536
    const int i = idx & 31, n = idx >> 5;
    const double f = (double)n * pow(10000.0, -(double)(2 * i) / 64.0);
    tab[idx * 2]     = (float)cos(f);
    tab[idx * 2 + 1] = (float)sin(f);
}

// ============================================================
// kernel_launch
// ============================================================
extern "C" void kernel_launch(void* const* d_in, const int* in_sizes, int n_in,
                              void* d_out, int out_size, void* d_ws, size_t ws_size,
                              hipStream_t stream)
{
    const float* x      = (const float*)d_in[0];
    const float* qkv_w  = (const float*)d_in[1];
    const float* proj_w = (const float*)d_in[2];
    const float* proj_b = (const float*)d_in[3];
    const float* w1_w   = (const float*)d_in[4];
    const float* w1_b   = (const float*)d_in[5];
    const float* w2_w   = (const float*)d_in[6];
    const float* w2_b   = (const float*)d_in[7];
    const float* w3_w   = (const float*)d_in[8];
    const float* w3_b   = (const float*)d_in[9];
    float* out = (float*)d_out;

    char* ws = (char*)d_ws;
    unsigned short* Qb    = (unsigned short*)(ws);              // [0,16M)
    unsigned short* Kb    = (unsigned short*)(ws + 16777216);   // [16,32M)
    unsigned short* Vtb   = (unsigned short*)(ws + 33554432);   // [32,48M)
    unsigned short* Ob    = (unsigned short*)(ws + 50331648);   // [48,64M)
    unsigned short* out1b = (unsigned short*)(ws + 67108864);   // [64,80M)
    unsigned short* w1b   = (unsigned short*)(ws + 83886080);   // [80,84M)
    unsigned short* w2b   = (unsigned short*)(ws + 88080384);   // [84,88M)
    unsigned short* w3b   = (unsigned short*)(ws + 92274688);   // [88,92M)
    unsigned short* projb = (unsigned short*)(ws + 96468992);   // [92,94M)
    unsigned short* xb    = (unsigned short*)(ws + 98566144);   // [94,110M)
    unsigned short* wqkvb = (unsigned short*)(ws + 115343360);  // [110,116M)
    float*          tab   = (float*)(ws + 121634816);           // [116,116.5M)
    unsigned short* hid   = (unsigned short*)(ws);              // [0,32M)

    const dim3 blk(256);

    // all fp32->bf16 conversions in one dispatch (18874368 elems / 1024)
    cvt_all<<<dim3(18432), blk, 0, stream>>>(
        x, qkv_w, proj_w, w1_w, w2_w, w3_w,
        xb, wqkvb, projb, w1b, w2b, w3b);
    rope_table<<<dim3(256), blk, 0, stream>>>(tab);

    // 1) QKV GEMM (8-phase 256^2) + fused rope/scale + V transpose
    mgemm_qkv<<<dim3(12, 32), dim3(512), 0, stream>>>(xb, wqkvb, tab, Qb, Kb, Vtb);
    // 2) MFMA flash attention; grid (bh, qt) -> same-bh blocks co-XCD
    attn_mfma<<<dim3(BATCH * NH, SEQ / 128), blk, 0, stream>>>(Qb, Kb, Vtb, Ob);
    // 3) out1b = Ob @ projb^T + proj_b (bf16)
    mgemm<1, true><<<dim3(8, 64), blk, 0, stream>>>(
        Ob, projb, proj_b, out1b, CDIM, CDIM);
    // 4) hid = silu(out1b@w1^T + b1) * (out1b@w2^T + b2)  [fused, no x2]
    mgemm_glu<<<dim3(32, 64), blk, 0, stream>>>(
        out1b, w1b, w2b, w1_b, w2_b, hid, 2048, CDIM);
    // 5) out = hid @ w3b^T + w3_b (fp32 -> d_out)
    mgemm<0, true><<<dim3(8, 64), blk, 0, stream>>>(
        hid, w3b, w3_b, out, CDIM, 2048);
}

// Round 11
// 422.798 us; speedup vs baseline: 1.3643x; 1.0485x over previous
//
#include <hip/hip_runtime.h>
#include <hip/hip_bf16.h>
#include <math.h>

// ---------------------------------------------------------------------------
// Round 20. R19: qkv 8-phase port WORKED (475.0 -> 443.3; qkv out of
// top-5). New leader mgemm_glu 93.4us (MfmaUtil 31%, conflicts 0) — same
// 2-phase regime qkv escaped. Change: mgemm_glu ported to the 8-phase
// 256^2 schedule with 32-row-interleaved B-tile (LDS rows q*64+0..31 =
// W1, q*64+32..63 = W2 for the same cols) so acc[m][0..1]=x1 and
// acc[m][2..3]=x2 for identical output columns -> intra-wave GLU combine,
// zero epilogue exchange. Grid (16,32), 512 thr, 128KB LDS.
// mgemm / mgemm_qkv(8ph) / attn / cvt_all unchanged (R19-proven).
// ---------------------------------------------------------------------------

#define SEQ     2048
#define BATCH   4
#define NH      16
#define CDIM    1024
#define MROWS   8192

typedef __bf16 bf16x8 __attribute__((ext_vector_type(8)));
typedef float  floatx4 __attribute__((ext_vector_type(4)));
typedef float  floatx16 __attribute__((ext_vector_type(16)));
typedef unsigned int u32;

__device__ __forceinline__ unsigned short f2bf(float f) {
    __bf16 h = (__bf16)f;                      // RNE, HW cvt on gfx950
    return __builtin_bit_cast(unsigned short, h);
}
__device__ __forceinline__ float fexp2(float x) {   // 2^x
    float r; asm("v_exp_f32 %0, %1" : "=v"(r) : "v"(x)); return r;
}
__device__ __forceinline__ float frcp(float x) {    // ~1ulp 1/x
    float r; asm("v_rcp_f32 %0, %1" : "=v"(r) : "v"(x)); return r;
}
__device__ __forceinline__ u32 cvtpk(float lo, float hi) {  // 2xbf16 word
    u32 w; asm("v_cvt_pk_bf16_f32 %0, %1, %2" : "=v"(w) : "v"(lo), "v"(hi));
    return w;
}
__device__ __forceinline__ floatx4 mfma16(bf16x8 a, bf16x8 b, floatx4 c) {
    return __builtin_amdgcn_mfma_f32_16x16x32_bf16(a, b, c, 0, 0, 0);
}
__device__ __forceinline__ floatx16 mfma32(bf16x8 a, bf16x8 b, floatx16 c) {
    return __builtin_amdgcn_mfma_f32_32x32x16_bf16(a, b, c, 0, 0, 0);
}
// async global->LDS, 16B/lane; LDS dest wave-uniform base + lane*16
__device__ __forceinline__ void gld16(void* lds, const void* g) {
    __builtin_amdgcn_global_load_lds(
        (const __attribute__((address_space(1))) u32*)g,
        (__attribute__((address_space(3))) u32*)lds, 16, 0, 0);
}
// counted-wait + raw barrier (no compiler vmcnt(0) drain at sync)
__device__ __forceinline__ void wait_vm0_barrier() {
    asm volatile("s_waitcnt vmcnt(0)" ::: "memory");
    __builtin_amdgcn_s_barrier();
    __builtin_amdgcn_sched_barrier(0);
}
__device__ __forceinline__ void raw_barrier() {
    __builtin_amdgcn_s_barrier();
    __builtin_amdgcn_sched_barrier(0);
}

// ============================================================
// bf16 MFMA GEMM NT, 2-phase dbuf + slab swizzle (R18-proven):
// C[m,n] = sum_k A[m,k]*B[n,k] (+bias)
// ============================================================
template <int OUTMODE, bool BIAS>
__global__ __launch_bounds__(256) void mgemm(
    const unsigned short* __restrict__ A,
    const unsigned short* __restrict__ B,
    const float* __restrict__ bias,
    void* __restrict__ C, int ldc,
    int K)
{
    __shared__ __align__(16) unsigned short As[2][128 * 32];
    __shared__ __align__(16) unsigned short Bs[2][128 * 32];

    const int tid  = threadIdx.x;
    const int lane = tid & 63;
    const int wave = tid >> 6;
    const int l16  = lane & 15;
    const int quad = lane >> 4;
    const int wm = (wave >> 1) * 64, wn = (wave & 1) * 64;
    const int bm = blockIdx.y, bn = blockIdx.x;

    const unsigned short* Ag = A + (size_t)(bm * 128) * K;
    const unsigned short* Bg = B + (size_t)(bn * 128) * K;

    const int srow0 = wave * 32 + (lane >> 2);
    const int scol  = 8 * ((lane & 3) ^ ((lane >> 3) & 3));
    const unsigned short* gA0 = Ag + (size_t)srow0 * K + scol;
    const unsigned short* gA1 = Ag + (size_t)(srow0 + 16) * K + scol;
    const unsigned short* gB0 = Bg + (size_t)srow0 * K + scol;
    const unsigned short* gB1 = Bg + (size_t)(srow0 + 16) * K + scol;

    auto stage = [&](int b, int kt) {
        gld16(&As[b][(wave * 2 + 0) * 512], gA0 + kt);
        gld16(&As[b][(wave * 2 + 1) * 512], gA1 + kt);
        gld16(&Bs[b][(wave * 2 + 0) * 512], gB0 + kt);
        gld16(&Bs[b][(wave * 2 + 1) * 512], gB1 + kt);
    };

    const int qsw = (quad ^ ((l16 >> 1) & 3)) * 8;

    floatx4 acc[4][4] = {};
    const int NK = K >> 5;

    stage(0, 0);
    wait_vm0_barrier();

    for (int i = 0; i < NK; ++i) {
        const int cur = i & 1;
        if (i + 1 < NK) stage(cur ^ 1, (i + 1) * 32);

        bf16x8 af[4], bfr[4];
        #pragma unroll
        for (int mt = 0; mt < 4; ++mt)
            af[mt] = *(const bf16x8*)&As[cur][(wm + mt * 16 + l16) * 32 + qsw];
        #pragma unroll
        for (int nt = 0; nt < 4; ++nt)
            bfr[nt] = *(const bf16x8*)&Bs[cur][(wn + nt * 16 + l16) * 32 + qsw];
        #pragma unroll
        for (int mt = 0; mt < 4; ++mt)
            #pragma unroll
            for (int nt = 0; nt < 4; ++nt)
                acc[mt][nt] = mfma16(af[mt], bfr[nt], acc[mt][nt]);

        if (i + 1 < NK) wait_vm0_barrier();
        else            raw_barrier();
    }

    #pragma unroll
    for (int nt = 0; nt < 4; ++nt) {
        const int gcol = bn * 128 + wn + nt * 16 + l16;
        const float bv = BIAS ? bias[gcol] : 0.0f;
        #pragma unroll
        for (int mt = 0; mt < 4; ++mt) {
            #pragma unroll
            for (int r = 0; r < 4; ++r) {
                const int grow = bm * 128 + wm + mt * 16 + quad * 4 + r;
                float v = acc[mt][nt][r] + bv;
                if (OUTMODE == 0)
                    ((float*)C)[(size_t)grow * ldc + gcol] = v;
                else
                    ((unsigned short*)C)[(size_t)grow * ldc + gcol] = f2bf(v);
            }
        }
    }
}

// ============================================================
// Shared 8-phase machinery (256^2 schedule, T3+T4+T5)
// ============================================================
#define RD_A(buf, mh)                                                     \
    { _Pragma("unroll") for (int i_ = 0; i_ < 4; ++i_) {                  \
        const int ro_ = (arow + ((mh) * 4 + i_) * 16) * 64;               \
        aF[i_][0] = *(const bf16x8*)&As[buf][ro_ + e0];                   \
        aF[i_][1] = *(const bf16x8*)&As[buf][ro_ + e1]; } }

#define RD_B(buf, nh)                                                     \
    { _Pragma("unroll") for (int n_ = 0; n_ < 2; ++n_) {                  \
        const int ro_ = (brow + ((nh) * 2 + n_) * 16) * 64;               \
        bF[nh][n_][0] = *(const bf16x8*)&Bs[buf][ro_ + e0];               \
        bF[nh][n_][1] = *(const bf16x8*)&Bs[buf][ro_ + e1]; } }

#define DO_MFMA(mh, nh)                                                   \
    { _Pragma("unroll") for (int i_ = 0; i_ < 4; ++i_)                    \
      { _Pragma("unroll") for (int n_ = 0; n_ < 2; ++n_) {                \
        acc[(mh)*4+i_][(nh)*2+n_] =                                       \
            mfma16(aF[i_][0], bF[nh][n_][0], acc[(mh)*4+i_][(nh)*2+n_]);  \
        acc[(mh)*4+i_][(nh)*2+n_] =                                       \
            mfma16(aF[i_][1], bF[nh][n_][1], acc[(mh)*4+i_][(nh)*2+n_]);  \
      } } }

#define PH_ENTER()                                                        \
    __builtin_amdgcn_s_barrier();                                         \
    asm volatile("s_waitcnt lgkmcnt(0)" ::: "memory");                    \
    __builtin_amdgcn_sched_barrier(0);                                    \
    __builtin_amdgcn_s_setprio(1)

#define PH_EXIT() __builtin_amdgcn_s_setprio(0)

// 8-phase main loop body (K=1024: 8 iters x 2 K-tiles x BK=64).
// stA/stB stage one half-tile (2x gld16/wave); hazards verified R19.
#define EIGHT_PHASE_LOOP()                                                \
    stA(0, 0, 0); stA(0, 1, 0); stB(0, 0, 0); stB(0, 1, 0);               \
    stA(1, 0, 64);                                                        \
    asm volatile("s_waitcnt vmcnt(2)" ::: "memory");                      \
    __builtin_amdgcn_s_barrier();                                         \
    __builtin_amdgcn_sched_barrier(0);                                    \
    for (int j = 0; j < 8; ++j) {                                         \
        const int k1 = (2 * j + 1) * 64;                                  \
        const int k2 = (2 * j + 2) * 64;                                  \
        const int k3 = (2 * j + 3) * 64;                                  \
        const bool more = (j < 7);                                        \
        RD_A(0, 0); RD_B(0, 0);                                           \
        stA(1, 1, k1);                                                    \
        PH_ENTER(); DO_MFMA(0, 0); PH_EXIT();                             \
        __builtin_amdgcn_s_barrier();                                     \
        RD_B(0, 1);                                                       \
        stB(1, 0, k1);                                                    \
        PH_ENTER(); DO_MFMA(0, 1); PH_EXIT();                             \
        __builtin_amdgcn_s_barrier();                                     \
        RD_A(0, 1);                                                       \
        stB(1, 1, k1);                                                    \
        PH_ENTER(); DO_MFMA(1, 1); PH_EXIT();                             \
        __builtin_amdgcn_s_barrier();                                     \
        if (more) stA(0, 0, k2);                                          \
        PH_ENTER(); DO_MFMA(1, 0); PH_EXIT();                             \
        if (more) { asm volatile("s_waitcnt vmcnt(2)" ::: "memory"); }    \
        else      { asm volatile("s_waitcnt vmcnt(0)" ::: "memory"); }    \
        __builtin_amdgcn_s_barrier();                                     \
        RD_A(1, 0); RD_B(1, 0);                                           \
        if (more) stA(0, 1, k2);                                          \
        PH_ENTER(); DO_MFMA(0, 0); PH_EXIT();                             \
        __builtin_amdgcn_s_barrier();                                     \
        RD_B(1, 1);                                                       \
        if (more) stB(0, 0, k2);                                          \
        PH_ENTER(); DO_MFMA(0, 1); PH_EXIT();                             \
        __builtin_amdgcn_s_barrier();                                     \
        RD_A(1, 1);                                                       \
        if (more) stB(0, 1, k2);                                          \
        PH_ENTER(); DO_MFMA(1, 1); PH_EXIT();                             \
        __builtin_amdgcn_s_barrier();                                     \
        if (more) stA(1, 0, k3);                                          \
        PH_ENTER(); DO_MFMA(1, 0); PH_EXIT();                             \
        if (more) {                                                       \
            asm volatile("s_waitcnt vmcnt(2)" ::: "memory");              \
            __builtin_amdgcn_s_barrier();                                 \
        }                                                                 \
    }

// ============================================================
// Fused SwiGLU GEMM — 8-phase 256^2 with 32-row-interleaved B-tile:
// Bs rows q*64+0..31 = W1 rows bn*128+q*32..+31 (same cols as)
// Bs rows q*64+32..63 = W2 rows bn*128+q*32..+31.
// => wave (wr,wc): acc[m][0..1] = x1, acc[m][2..3] = x2 for hid cols
// bn*128 + wc*32 + nt*16 + l16  -> intra-wave silu(x1)*x2 combine.
// Block output: 256 rows x 128 hid-cols; grid (16, 32).
// ============================================================
__global__ __launch_bounds__(512, 2) void mgemm_glu(
    const unsigned short* __restrict__ B1p,
    const unsigned short* __restrict__ B2p,
    const unsigned short* __restrict__ A,
    const float* __restrict__ bias1,
    const float* __restrict__ bias2,
    unsigned short* __restrict__ C, int ldc)
{
    __shared__ __align__(16) unsigned short As[2][256 * 64];
    __shared__ __align__(16) unsigned short Bs[2][256 * 64];

    const int tid  = threadIdx.x;
    const int lane = tid & 63;
    const int wave = tid >> 6;          // 0..7
    const int l16  = lane & 15;
    const int quad = lane >> 4;
    const int wr   = wave >> 2;         // M half (0..1)
    const int wc   = wave & 3;          // N quarter (0..3)
    const int bn = blockIdx.x, bm = blockIdx.y;
    const int K = CDIM;

    const unsigned short* Ag = A + (size_t)(bm * 256) * K;

    const int srow  = lane >> 3;
    const int sgcol = ((lane & 7) ^ srow) * 8;

    auto stA = [&](int buf, int half, int kt) {
        #pragma unroll
        for (int s = 0; s < 2; ++s) {
            const int rbase = half * 128 + (wave * 2 + s) * 8;
            gld16(&As[buf][rbase * 64],
                  Ag + (size_t)(rbase + srow) * K + kt + sgcol);
        }
    };
    // interleaved B: LDS row rho -> q=rho>>6, r6=rho&63;
    // r6<32 -> W1 row bn*128+q*32+r6 ; else W2 row bn*128+q*32+(r6-32)
    auto stB = [&](int buf, int half, int kt) {
        #pragma unroll
        for (int s = 0; s < 2; ++s) {
            const int rbase = half * 128 + (wave * 2 + s) * 8;
            const int q = rbase >> 6, r6 = rbase & 63;
            const unsigned short* src = (r6 < 32)
                ? B1p + (size_t)(bn * 128 + q * 32 + r6) * K
                : B2p + (size_t)(bn * 128 + q * 32 + (r6 - 32)) * K;
            gld16(&Bs[buf][rbase * 64],
                  src + (size_t)srow * K + kt + sgcol);
        }
    };

    const int e0 = ((quad)     ^ (l16 & 7)) * 8;
    const int e1 = ((quad + 4) ^ (l16 & 7)) * 8;
    const int arow = wr * 128 + l16;
    const int brow = wc * 64 + l16;

    floatx4 acc[8][4] = {};
    bf16x8 aF[4][2];
    bf16x8 bF[2][2][2];

    EIGHT_PHASE_LOOP();

    // epilogue: intra-wave GLU combine, fast silu
    #pragma unroll
    for (int nt = 0; nt < 2; ++nt) {
        const int gcol = bn * 128 + wc * 32 + nt * 16 + l16;
        const float b1 = bias1[gcol];
        const float b2 = bias2[gcol];
        #pragma unroll
        for (int m = 0; m < 8; ++m) {
            #pragma unroll
            for (int r = 0; r < 4; ++r) {
                const int grow = bm * 256 + wr * 128 + m * 16 + quad * 4 + r;
                const float x1 = acc[m][nt][r] + b1;
                const float x2 = acc[m][nt + 2][r] + b2;
                const float e = fexp2(x1 * -1.44269504088896f);
                const float v = x1 * frcp(1.0f + e) * x2;
                C[(size_t)grow * ldc + gcol] = f2bf(v);
            }
        }
    }
}

// ============================================================
// QKV GEMM — 8-phase 256^2 (R19-PROVEN, unchanged):
// ============================================================
__global__ __launch_bounds__(512, 2) void mgemm_qkv(
    const unsigned short* __restrict__ A,
    const unsigned short* __restrict__ B,
    const float* __restrict__ tab,
    unsigned short* __restrict__ Qb,
    unsigned short* __restrict__ Kb,
    unsigned short* __restrict__ Vtb)
{
    __shared__ __align__(16) unsigned short As[2][256 * 64];
    __shared__ __align__(16) unsigned short Bs[2][256 * 64];

    const int tid  = threadIdx.x;
    const int lane = tid & 63;
    const int wave = tid >> 6;          // 0..7
    const int l16  = lane & 15;
    const int quad = lane >> 4;
    const int wr   = wave >> 2;         // M half (0..1)
    const int wc   = wave & 3;          // N quarter (0..3)
    const int bn = blockIdx.x, bm = blockIdx.y;
    const int K = CDIM;

    const unsigned short* Ag = A + (size_t)(bm * 256) * K;
    const unsigned short* Bg = B + (size_t)(bn * 256) * K;

    const int srow  = lane >> 3;
    const int sgcol = ((lane & 7) ^ srow) * 8;

    auto stA = [&](int buf, int half, int kt) {
        #pragma unroll
        for (int s = 0; s < 2; ++s) {
            const int rbase = half * 128 + (wave * 2 + s) * 8;
            gld16(&As[buf][rbase * 64],
                  Ag + (size_t)(rbase + srow) * K + kt + sgcol);
        }
    };
    auto stB = [&](int buf, int half, int kt) {
        #pragma unroll
        for (int s = 0; s < 2; ++s) {
            const int rbase = half * 128 + (wave * 2 + s) * 8;
            gld16(&Bs[buf][rbase * 64],
                  Bg + (size_t)(rbase + srow) * K + kt + sgcol);
        }
    };

    const int e0 = ((quad)     ^ (l16 & 7)) * 8;
    const int e1 = ((quad + 4) ^ (l16 & 7)) * 8;
    const int arow = wr * 128 + l16;
    const int brow = wc * 64 + l16;

    floatx4 acc[8][4] = {};
    bf16x8 aF[4][2];
    bf16x8 bF[2][2][2];

    EIGHT_PHASE_LOOP();

    // ---- epilogues ----
    const int part = bn >> 2;           // 0=q 1=k 2=v (256-col blocks)

    if (part == 2) {
        // V: transpose via LDS (As dead) -> Vtb [bh][d][n], 32B stores
        unsigned short* T = &As[0][0];  // [2][256][16] ushort = 16 KB
        #pragma unroll
        for (int m = 0; m < 8; ++m) {
            __syncthreads();
            #pragma unroll
            for (int n = 0; n < 4; ++n) {
                ushort4 pk;
                pk.x = f2bf(acc[m][n][0]); pk.y = f2bf(acc[m][n][1]);
                pk.z = f2bf(acc[m][n][2]); pk.w = f2bf(acc[m][n][3]);
                *(ushort4*)&T[(wr * 256 + wc * 64 + n * 16 + l16) * 16 + quad * 4] = pk;
            }
            __syncthreads();
            // 512 threads: wr2 = tid>>8, col = tid&255; 32B along n
            const int wr2 = tid >> 8, col = tid & 255;
            const int grow0 = bm * 256 + wr2 * 128 + m * 16;
            const int b = grow0 >> 11, n0 = grow0 & 2047;
            const int h2 = (bn & 3) * 4 + (col >> 6);
            const int d  = col & 63;
            unsigned short* dst = Vtb +
                ((size_t)(b * NH + h2) * 64 + d) * 2048 + n0;
            const int tb = (wr2 * 256 + col) * 16;
            *(uint4*)dst       = *(const uint4*)&T[tb];
            *(uint4*)(dst + 8) = *(const uint4*)&T[tb + 8];
        }
    } else {
        // q/k: fp32 RoPE; q scaled by 0.125*log2e (exp2 softmax)
        const float qscale = (part == 0) ? 0.125f * 1.44269504088896f : 1.0f;
        const int h = (bn & 3) * 4 + wc;
        unsigned short* qk = (part == 0) ? Qb : Kb;
        #pragma unroll
        for (int m = 0; m < 8; ++m) {
            #pragma unroll
            for (int r = 0; r < 4; ++r) {
                const int grow = bm * 256 + wr * 128 + m * 16 + quad * 4 + r;
                const int b = grow >> 11, n = grow & 2047;
                unsigned short* dst = qk + ((size_t)(b * NH + h) * 2048 + n) * 64;
                #pragma unroll
                for (int nt = 0; nt < 2; ++nt) {
                    const int i = nt * 16 + l16;          // 0..31
                    const float c  = tab[(n * 32 + i) * 2];
                    const float sn = tab[(n * 32 + i) * 2 + 1];
                    const float x1  = acc[m][nt][r];
                    const float x2v = acc[m][nt + 2][r];
                    dst[i]      = f2bf((x1 * c - x2v * sn) * qscale);
                    dst[i + 32] = f2bf((x2v * c + x1 * sn) * qscale);
                }
            }
        }
    }
}

// ============================================================
// MFMA flash attention v4 (PROVEN R14/R15): 128q blocks, 32x32x16,
// P in registers via cvt_pk + permlane32_swap. Grid (bh, qt).
// ============================================================
__global__ __launch_bounds__(256) void attn_mfma(
    const unsigned short* __restrict__ Qb,
    const unsigned short* __restrict__ Kb,
    const unsigned short* __restrict__ Vtb,
    unsigned short* __restrict__ Ob)
{
    const int bh = blockIdx.x;        // 0..63  (x-major: same-bh -> same XCD)
    const int qt = blockIdx.y;        // 0..15
    const int tid = threadIdx.x;
    const int lane = tid & 63, wave = tid >> 6;
    const int r32 = lane & 31, hi = lane >> 5;
    const int qrow = wave * 32 + r32; // this lane's query row in LDS

    __shared__ unsigned short QP[128][72];  // Q staging (held all iters)
    __shared__ unsigned short Ks[64][72];   // K tile [key][dim]
    __shared__ unsigned short Vs[64][72];   // V^T tile [dim][key]

    const unsigned short* Qg = Qb + ((size_t)bh * 2048 + qt * 128) * 64;
    const unsigned short* Kg = Kb + (size_t)bh * 2048 * 64;
    const unsigned short* Vg = Vtb + (size_t)bh * 64 * 2048;

    // stage Q tile 128x64
    #pragma unroll
    for (int rep = 0; rep < 4; ++rep) {
        const int c = tid + rep * 256;
        const int r = c >> 3, d0 = (c & 7) * 8;
        *(uint4*)&QP[r][d0] = *(const uint4*)(Qg + (size_t)r * 64 + d0);
    }

    // K/V staging slots for this thread (2 b128 each per tile)
    const int c0 = tid, c1 = tid + 256;
    const int kr0 = c0 >> 3, kd0 = (c0 & 7) * 8;
    const int kr1 = c1 >> 3, kd1 = (c1 & 7) * 8;

    // T14 prefetch tile 0 into regs
    uint4 ka0 = *(const uint4*)(Kg + (size_t)kr0 * 64 + kd0);
    uint4 ka1 = *(const uint4*)(Kg + (size_t)kr1 * 64 + kd1);
    uint4 va0 = *(const uint4*)(Vg + (size_t)kr0 * 2048 + kd0);
    uint4 va1 = *(const uint4*)(Vg + (size_t)kr1 * 2048 + kd1);

    __syncthreads();   // Q tile ready

    // Q B-frags (rows = wave's 32 queries), held for all iterations
    bf16x8 bq[4];
    #pragma unroll
    for (int f = 0; f < 4; ++f)
        bq[f] = *(const bf16x8*)&QP[qrow][f * 16 + hi * 8];

    floatx16 o0 = {}, o1 = {};      // O^T[d][q]: d-tiles 0..31 / 32..63
    float l_acc = 0.0f;

    for (int kt = 0; kt < 32; ++kt) {
        __syncthreads();   // prev tile's Ks/Vs frag reads complete
        *(uint4*)&Ks[kr0][kd0] = ka0;
        *(uint4*)&Ks[kr1][kd1] = ka1;
        *(uint4*)&Vs[kr0][kd0] = va0;
        *(uint4*)&Vs[kr1][kd1] = va1;
        if (kt + 1 < 32) {           // T14: issue next-tile loads now,
            const size_t nb = (size_t)(kt + 1) * 64;     // land during compute
            ka0 = *(const uint4*)(Kg + (nb + kr0) * 64 + kd0);
            ka1 = *(const uint4*)(Kg + (nb + kr1) * 64 + kd1);
            va0 = *(const uint4*)(Vg + (size_t)kr0 * 2048 + nb + kd0);
            va1 = *(const uint4*)(Vg + (size_t)kr1 * 2048 + nb + kd1);
        }
        __syncthreads();   // tile ready

        // ---- per 32-key subtile: S^T -> exp2 -> in-reg P -> PV ----
        #pragma unroll
        for (int t = 0; t < 2; ++t) {
            floatx16 s = {};
            #pragma unroll
            for (int f = 0; f < 4; ++f) {
                const bf16x8 ak = *(const bf16x8*)&Ks[t * 32 + r32][f * 16 + hi * 8];
                s = mfma32(ak, bq[f], s);
            }
            // p = exp2(s); rowsum
            float p[16];
            float rs = 0.0f;
            #pragma unroll
            for (int g = 0; g < 16; ++g) { p[g] = fexp2(s[g]); rs += p[g]; }
            l_acc += rs;
            // pack to bf16 words and swap halves across hi
            u32 w0 = cvtpk(p[0], p[1]),   w2 = cvtpk(p[4], p[5]);
            u32 w1 = cvtpk(p[2], p[3]),   w3 = cvtpk(p[6], p[7]);
            u32 w4 = cvtpk(p[8], p[9]),   w6 = cvtpk(p[12], p[13]);
            u32 w5 = cvtpk(p[10], p[11]), w7 = cvtpk(p[14], p[15]);
            asm("v_permlane32_swap_b32 %0, %1" : "+v"(w0), "+v"(w2));
            asm("v_permlane32_swap_b32 %0, %1" : "+v"(w1), "+v"(w3));
            asm("v_permlane32_swap_b32 %0, %1" : "+v"(w4), "+v"(w6));
            asm("v_permlane32_swap_b32 %0, %1" : "+v"(w5), "+v"(w7));
            uint4 u0; u0.x = w0; u0.y = w1; u0.z = w2; u0.w = w3;
            uint4 u1; u1.x = w4; u1.y = w5; u1.z = w6; u1.w = w7;
            const bf16x8 bp0 = __builtin_bit_cast(bf16x8, u0);  // keys t*32 + slot0
            const bf16x8 bp1 = __builtin_bit_cast(bf16x8, u1);  // keys t*32 + slot1
            // PV for this subtile's two 16-key slots (f = 2t, 2t+1)
            {
                const int f0 = 2 * t, f1 = 2 * t + 1;
                const bf16x8 av00 = *(const bf16x8*)&Vs[r32][f0 * 16 + hi * 8];
                const bf16x8 av01 = *(const bf16x8*)&Vs[32 + r32][f0 * 16 + hi * 8];
                o0 = mfma32(av00, bp0, o0);
                o1 = mfma32(av01, bp0, o1);
                const bf16x8 av10 = *(const bf16x8*)&Vs[r32][f1 * 16 + hi * 8];
                const bf16x8 av11 = *(const bf16x8*)&Vs[32 + r32][f1 * 16 + hi * 8];
                o0 = mfma32(av10, bp1, o0);
                o1 = mfma32(av11, bp1, o1);
            }
        }
    }

    // epilogue: lane's query = wave*32 + r32; lanes l/l+32 hold disjoint key
    // halves of the same query -> one shfl to complete l.
    const float l_tot = l_acc + __shfl_xor(l_acc, 32);
    const float inv = 1.0f / l_tot;
    const int b = bh >> 4, h = bh & 15;
    unsigned short* orow = Ob +
        (size_t)(b * SEQ + qt * 128 + qrow) * CDIM + h * 64;
    #pragma unroll
    for (int u = 0; u < 2; ++u) {
        const floatx16 ov = u ? o1 : o0;
        #pragma unroll
        for (int g = 0; g < 4; ++g) {
            ushort4 pk;
            pk.x = f2bf(ov[4 * g + 0] * inv); pk.y = f2bf(ov[4 * g + 1] * inv);
            pk.z = f2bf(ov[4 * g + 2] * inv); pk.w = f2bf(ov[4 * g + 3] * inv);
            // d = u*32 + 8g + 4*hi + (0..3)
            *(ushort4*)(orow + u * 32 + 8 * g + 4 * hi) = pk;
        }
    }
}

// ============================================================
// One-shot fp32 -> bf16 for all six tensors (block-uniform segments);
// RoPE table (fp64 angles)
// ============================================================
__global__ __launch_bounds__(256) void cvt_all(
    const float* __restrict__ x,    const float* __restrict__ qkv,
    const float* __restrict__ proj, const float* __restrict__ w1,
    const float* __restrict__ w2,   const float* __restrict__ w3,
    unsigned short* __restrict__ xb,    unsigned short* __restrict__ qkvb,
    unsigned short* __restrict__ projb, unsigned short* __restrict__ w1b,
    unsigned short* __restrict__ w2b,   unsigned short* __restrict__ w3b)
{
    const size_t i = ((size_t)blockIdx.x * 256 + threadIdx.x) * 4;
    const float* src; unsigned short* dst; size_t off;
    if      (i <  8388608) { src = x;    dst = xb;    off = 0; }
    else if (i < 11534336) { src = qkv;  dst = qkvb;  off = 8388608; }
    else if (i < 12582912) { src = proj; dst = projb; off = 11534336; }
    else if (i < 14680064) { src = w1;   dst = w1b;   off = 12582912; }
    else if (i < 16777216) { src = w2;   dst = w2b;   off = 14680064; }
    else                   { src = w3;   dst = w3b;   off = 16777216; }
    const size_t j = i - off;
    const float4 f = *(const float4*)(src + j);
    ushort4 o; o.x = f2bf(f.x); o.y = f2bf(f.y); o.z = f2bf(f.z); o.w = f2bf(f.w);
    *(ushort4*)(dst + j) = o;
}

__global__ __launch_bounds__(256) void rope_table(float* __restrict__ tab)
{
    const int idx = blockIdx.x * 256 + threadIdx.x;   // < 65536
    const int i = idx & 31, n = idx >> 5;
    const double f = (double)n * pow(10000.0, -(double)(2 * i) / 64.0);
    tab[idx * 2]     = (float)cos(f);
    tab[idx * 2 + 1] = (float)sin(f);
}

// ============================================================
// kernel_launch
// ============================================================
extern "C" void kernel_launch(void* const* d_in, const int* in_sizes, int n_in,
                              void* d_out, int out_size, void* d_ws, size_t ws_size,
                              hipStream_t stream)
{
    const float* x      = (const float*)d_in[0];
    const float* qkv_w  = (const float*)d_in[1];
    const float* proj_w = (const float*)d_in[2];
    const float* proj_b = (const float*)d_in[3];
    const float* w1_w   = (const float*)d_in[4];
    const float* w1_b   = (const float*)d_in[5];
    const float* w2_w   = (const float*)d_in[6];
    const float* w2_b   = (const float*)d_in[7];
    const float* w3_w   = (const float*)d_in[8];
    const float* w3_b   = (const float*)d_in[9];
    float* out = (float*)d_out;

    char* ws = (char*)d_ws;
    unsigned short* Qb    = (unsigned short*)(ws);              // [0,16M)
    unsigned short* Kb    = (unsigned short*)(ws + 16777216);   // [16,32M)
    unsigned short* Vtb   = (unsigned short*)(ws + 33554432);   // [32,48M)
    unsigned short* Ob    = (unsigned short*)(ws + 50331648);   // [48,64M)
    unsigned short* out1b = (unsigned short*)(ws + 67108864);   // [64,80M)
    unsigned short* w1b   = (unsigned short*)(ws + 83886080);   // [80,84M)
    unsigned short* w2b   = (unsigned short*)(ws + 88080384);   // [84,88M)
    unsigned short* w3b   = (unsigned short*)(ws + 92274688);   // [88,92M)
    unsigned short* projb = (unsigned short*)(ws + 96468992);   // [92,94M)
    unsigned short* xb    = (unsigned short*)(ws + 98566144);   // [94,110M)
    unsigned short* wqkvb = (unsigned short*)(ws + 115343360);  // [110,116M)
    float*          tab   = (float*)(ws + 121634816);           // [116,116.5M)
    unsigned short* hid   = (unsigned short*)(ws);              // [0,32M)

    const dim3 blk(256);

    // all fp32->bf16 conversions in one dispatch (18874368 elems / 1024)
    cvt_all<<<dim3(18432), blk, 0, stream>>>(
        x, qkv_w, proj_w, w1_w, w2_w, w3_w,
        xb, wqkvb, projb, w1b, w2b, w3b);
    rope_table<<<dim3(256), blk, 0, stream>>>(tab);

    // 1) QKV GEMM (8-phase 256^2) + fused rope/scale + V transpose
    mgemm_qkv<<<dim3(12, 32), dim3(512), 0, stream>>>(xb, wqkvb, tab, Qb, Kb, Vtb);
    // 2) MFMA flash attention; grid (bh, qt) -> same-bh blocks co-XCD
    attn_mfma<<<dim3(BATCH * NH, SEQ / 128), blk, 0, stream>>>(Qb, Kb, Vtb, Ob);
    // 3) out1b = Ob @ projb^T + proj_b (bf16)
    mgemm<1, true><<<dim3(8, 64), blk, 0, stream>>>(
        Ob, projb, proj_b, out1b, CDIM, CDIM);
    // 4) hid = silu(out1b@w1^T + b1) * (out1b@w2^T + b2)  [8-phase fused]
    mgemm_glu<<<dim3(16, 32), dim3(512), 0, stream>>>(
        w1b, w2b, out1b, w1_b, w2_b, hid, 2048);
    // 5) out = hid @ w3b^T + w3_b (fp32 -> d_out)
    mgemm<0, true><<<dim3(8, 64), blk, 0, stream>>>(
        hid, w3b, w3_b, out, CDIM, 2048);
}